// Round 8
// baseline (407.919 us; speedup 1.0000x reference)
//
#include <hip/hip_runtime.h>
#include <hip/hip_bf16.h>
#include <cstdint>
#include <cstddef>

#define EMBED 768
#define STREAMS 4
#define CHUNK 192          // EMBED / STREAMS
#define HEADS 12
#define HD 64
#define SEQ 1024
#define BATCH 8
#define TOKENS (BATCH * SEQ)   // 8192
#define MLPH 3072

typedef __bf16 bf16;
typedef __bf16 bf16x4 __attribute__((ext_vector_type(4)));
typedef __bf16 bf16x8 __attribute__((ext_vector_type(8)));
typedef float f32x4 __attribute__((ext_vector_type(4)));
typedef float f32x16 __attribute__((ext_vector_type(16)));

// async global->LDS, 16B per lane; LDS dest must be linear in lane order
#define GLDS16(gp, lp)                                                        \
  __builtin_amdgcn_global_load_lds(                                           \
      (const __attribute__((address_space(1))) void*)(gp),                    \
      (__attribute__((address_space(3))) void*)(lp), 16, 0, 0)

// raw barrier (no vmcnt(0) drain) with compiler memory fences on both sides
#define BARRIER() do { asm volatile("" ::: "memory");                         \
  __builtin_amdgcn_s_barrier(); asm volatile("" ::: "memory"); } while (0)

// ---------------------------------------------------------------- hprep ----
__global__ void hprep_kernel(const float* ar, const float* ap, const float* ao,
                             const float* mr, const float* mp, const float* mo,
                             float* HS) {
  if (threadIdx.x != 0) return;
  const float* L[2] = {ar, mr};
  const float* P[2] = {ap, mp};
  const float* O[2] = {ao, mo};
  for (int s = 0; s < 2; ++s) {
    float A[16];
    for (int i = 0; i < 16; ++i) A[i] = expf(L[s][i]);
    for (int it = 0; it < 20; ++it) {
      for (int r = 0; r < 4; ++r) {
        float rs = A[4*r] + A[4*r+1] + A[4*r+2] + A[4*r+3] + 1e-8f;
        for (int c = 0; c < 4; ++c) A[4*r+c] /= rs;
      }
      for (int c = 0; c < 4; ++c) {
        float cs = A[c] + A[4+c] + A[8+c] + A[12+c] + 1e-8f;
        for (int r = 0; r < 4; ++r) A[4*r+c] /= cs;
      }
    }
    float* dst = HS + s * 24;
    for (int i = 0; i < 16; ++i) dst[i] = A[i];
    {
      float m = fmaxf(fmaxf(P[s][0], P[s][1]), fmaxf(P[s][2], P[s][3]));
      float e[4], t = 0.f;
      for (int i = 0; i < 4; ++i) { e[i] = expf(P[s][i] - m); t += e[i]; }
      for (int i = 0; i < 4; ++i) dst[16 + i] = e[i] / t;
    }
    {
      float m = fmaxf(fmaxf(O[s][0], O[s][1]), fmaxf(O[s][2], O[s][3]));
      float e[4], t = 0.f;
      for (int i = 0; i < 4; ++i) { e[i] = expf(O[s][i] - m); t += e[i]; }
      for (int i = 0; i < 4; ++i) dst[20 + i] = e[i] / t;
    }
  }
}

// ------------------------------------------------------------------ cvt ----
__global__ void cvt_kernel(const float* __restrict__ in, bf16* __restrict__ out, int n4) {
  int i = blockIdx.x * 256 + threadIdx.x;
  const int st = gridDim.x * 256;
  for (; i < n4; i += st) {
    const float4 v = ((const float4*)in)[i];
    bf16x4 o = {(bf16)v.x, (bf16)v.y, (bf16)v.z, (bf16)v.w};
    *(bf16x4*)(out + (size_t)i * 4) = o;
  }
}

// ---------------------------------------------------------------- preln ----
__global__ __launch_bounds__(256) void preln_kernel(
    const float* __restrict__ x, const float* __restrict__ H,
    const float* __restrict__ g, const float* __restrict__ b,
    bf16* __restrict__ out) {
  const int t = blockIdx.x;
  const float* xr = x + (size_t)t * EMBED;
  __shared__ float s[CHUNK];
  __shared__ float part[8];
  __shared__ float red[2];
  const int tid = threadIdx.x;
  float sv = 0.f;
  if (tid < CHUNK) {
    sv = H[0]*xr[tid] + H[1]*xr[CHUNK+tid] + H[2]*xr[2*CHUNK+tid] + H[3]*xr[3*CHUNK+tid];
    s[tid] = sv;
  }
  float sum = sv, sq = sv * sv;
  #pragma unroll
  for (int m = 32; m > 0; m >>= 1) {
    sum += __shfl_down(sum, m);
    sq  += __shfl_down(sq, m);
  }
  if ((tid & 63) == 0) { part[tid >> 6] = sum; part[4 + (tid >> 6)] = sq; }
  __syncthreads();
  if (tid == 0) {
    float S = part[0] + part[1] + part[2] + part[3];
    float Q = part[4] + part[5] + part[6] + part[7];
    float mu = S * (1.f / CHUNK);
    float var = Q * (1.f / CHUNK) - mu * mu;
    red[0] = mu;
    red[1] = rsqrtf(var + 1e-5f);
  }
  __syncthreads();
  const float mu = red[0], rs = red[1];
  bf16* orow = out + (size_t)t * EMBED;
  #pragma unroll
  for (int r = 0; r < 3; ++r) {
    const int d = tid + r * 256;
    const float v = (s[d % CHUNK] - mu) * rs * g[d] + b[d];
    orow[d] = (bf16)v;
  }
}

// ----------------------------------------------------------------- gemm ----
// C[m,n] = sum_k A[m,k]*B[n,k] + bias[n]; bf16 row-major A (MxK), B (NxK).
// 128x128 tile, BK=32, 32x32x16 MFMA, FOUR-buffer LDS pipeline (3-deep
// prefetch, vmcnt(12) steady state) — staging latency ~1400cy fully hidden.
// T5 setprio around the MFMA cluster. T1 XCD block swizzle (nwg % 8 == 0).
// KSPLIT=2: blockIdx.z halves K; z=1 writes partial to C1 (no bias).
// LDS swizzle: granule ^= (row>>1)&3 (bank period of 64B row = 2 rows);
// staging pre-swizzles the global source, LDS dest linear (rule #21).
template <int GELU, int OUTF32, int KSPLIT>
__global__ __launch_bounds__(256, 2) void gemm_bt(
    const bf16* __restrict__ A, const bf16* __restrict__ B,
    const float* __restrict__ bias, void* __restrict__ C0,
    void* __restrict__ C1, int M, int N, int K) {
  constexpr int BM = 128, BN = 128, BK = 32;
  __shared__ bf16 sA[4][BM * BK];
  __shared__ bf16 sB[4][BN * BK];
  const int tid  = threadIdx.x;
  const int lane = tid & 63;
  const int nwg = gridDim.x * gridDim.y;
  int Lw = blockIdx.y * gridDim.x + blockIdx.x;
  Lw = (Lw & 7) * (nwg >> 3) + (Lw >> 3);
  const int bm = (Lw / gridDim.x) * BM;
  const int bn = (Lw % gridDim.x) * BN;
  const int wave = tid >> 6;
  const int wr = (wave >> 1) * 64;
  const int wc = (wave & 1) * 64;
  f32x16 acc[2][2] = {};
  const int tr = tid >> 2;
  const int gt = tid & 3;
  const int gsw = (gt ^ ((tr >> 1) & 3)) * 8;   // inverse-swizzled source granule
  const int kbeg = (KSPLIT > 1) ? blockIdx.z * (K / KSPLIT) : 0;
  const bf16* Ag = A + (size_t)(bm + tr) * K + kbeg + gsw;
  const bf16* Bg = B + (size_t)(bn + tr) * K + kbeg + gsw;
  const int lofs = tr * BK + gt * 8;
  const int r31 = lane & 31, rh = lane >> 5;
  const int asw = (r31 >> 1) & 3;               // read-side swizzle (row bits 2:1)
  const int nst = K / KSPLIT / BK;
#define STAGE(buf, t)                                                         \
  do { const int bk_ = (t) * BK;                                              \
    GLDS16(Ag + bk_, sA[buf] + lofs);                                         \
    GLDS16(Ag + (size_t)64 * K + bk_, sA[buf] + lofs + 64 * BK);              \
    GLDS16(Bg + bk_, sB[buf] + lofs);                                         \
    GLDS16(Bg + (size_t)64 * K + bk_, sB[buf] + lofs + 64 * BK);              \
  } while (0)
  STAGE(0, 0);
  STAGE(1, 1);
  STAGE(2, 2);
  for (int t = 0; t < nst; ++t) {
    const int cur = t & 3;
    if (t + 3 < nst) {
      STAGE((t + 3) & 3, t + 3);
      asm volatile("s_waitcnt vmcnt(12)" ::: "memory");
    } else if (t + 2 < nst) {
      asm volatile("s_waitcnt vmcnt(8)" ::: "memory");
    } else if (t + 1 < nst) {
      asm volatile("s_waitcnt vmcnt(4)" ::: "memory");
    } else {
      asm volatile("s_waitcnt vmcnt(0)" ::: "memory");
    }
    BARRIER();
    bf16x8 af[2][2], bfr[2][2];
    #pragma unroll
    for (int ks = 0; ks < 2; ++ks) {
      const int pos = ((ks * 2 + rh) ^ asw) * 8;
      #pragma unroll
      for (int i = 0; i < 2; ++i) {
        af[i][ks]  = *(const bf16x8*)(sA[cur] + (wr + i * 32 + r31) * BK + pos);
        bfr[i][ks] = *(const bf16x8*)(sB[cur] + (wc + i * 32 + r31) * BK + pos);
      }
    }
    __builtin_amdgcn_s_setprio(1);
    #pragma unroll
    for (int ks = 0; ks < 2; ++ks)
      #pragma unroll
      for (int i = 0; i < 2; ++i)
        #pragma unroll
        for (int j = 0; j < 2; ++j)
          acc[i][j] = __builtin_amdgcn_mfma_f32_32x32x16_bf16(af[i][ks], bfr[j][ks], acc[i][j], 0, 0, 0);
    __builtin_amdgcn_s_setprio(0);
    BARRIER();
  }
#undef STAGE
  // C/D 32x32 layout: col = lane&31, row = (reg&3) + 8*(reg>>2) + 4*(lane>>5)
  const bool second = (KSPLIT > 1) && (blockIdx.z != 0);
  void* Co = second ? C1 : C0;
  #pragma unroll
  for (int j = 0; j < 2; ++j) {
    const int col = bn + wc + j * 32 + r31;
    const float bv = second ? 0.f : bias[col];
    #pragma unroll
    for (int i = 0; i < 2; ++i) {
      const int row0 = bm + wr + i * 32 + 4 * rh;
      #pragma unroll
      for (int reg = 0; reg < 16; ++reg) {
        const int row = row0 + (reg & 3) + 8 * (reg >> 2);
        float v = acc[i][j][reg] + bv;
        if (GELU) v = 0.5f * v * (1.f + erff(v * 0.70710678118654752f));
        const size_t off = (size_t)row * N + col;
        if (OUTF32) ((float*)Co)[off] = v;
        else        ((bf16*)Co)[off] = (bf16)v;
      }
    }
  }
}

// ------------------------------------------------------------------- vt ----
// VT[bh][hd][tok] = qkv[bb*1024+tok][1536 + h*64 + hd]; swizzled LDS stage.
__global__ __launch_bounds__(256) void vt_kernel(const bf16* __restrict__ qkv,
                                                 bf16* __restrict__ VT) {
  const int tt = blockIdx.x;   // 16 tok tiles of 64
  const int bh = blockIdx.y;   // 96
  const int bb = bh / HEADS;
  const int h = bh - bb * HEADS;
  __shared__ bf16 sT[64 * 64];
  const int t = threadIdx.x;
  const int srow = t >> 3;            // 0..31 (tok within half-tile)
  const int g = t & 7;                // 16B granule
  const int gs = ((g ^ (srow & 7)) * 8);
  const bf16* Vg = qkv + ((size_t)(bb * SEQ + tt * 64 + srow)) * 2304 + 1536 + h * 64;
  GLDS16(Vg + gs, sT + srow * 64 + g * 8);
  GLDS16(Vg + (size_t)32 * 2304 + gs, sT + (32 + srow) * 64 + g * 8);
  __syncthreads();
  const int hd = t >> 2;
  const int tg = (t & 3) * 16;
  bf16 tmp[16];
  #pragma unroll
  for (int j = 0; j < 16; ++j) {
    const int tok = tg + j;
    tmp[j] = sT[tok * 64 + (hd ^ ((tok & 7) << 3))];
  }
  bf16* op = VT + (size_t)bh * (HD * SEQ) + (size_t)hd * SEQ + tt * 64 + tg;
  *(bf16x8*)(op) = *(const bf16x8*)(tmp);
  *(bf16x8*)(op + 8) = *(const bf16x8*)(tmp + 8);
}

// ----------------------------------------------------------------- attn ----
// Flash attention, swizzled LDS, double-buffered K/V (T3-min), row-sum via
// ones-row MFMA, exact defer-rescale, bh-major XCD-chunked block mapping,
// T5 setprio around MFMA clusters.
__global__ __launch_bounds__(256) void attn_kernel(
    const bf16* __restrict__ qkv, const bf16* __restrict__ VT,
    bf16* __restrict__ out) {
  const int lin = blockIdx.x;
  const int qt = (lin >> 3) & 15;
  const int bh = (lin & 7) + 8 * (lin >> 7);
  const int bb = bh / HEADS;
  const int h = bh - bb * HEADS;
  const int tid = threadIdx.x;
  const int lane = tid & 63;
  const int wave = tid >> 6;
  const size_t tokBase = (size_t)bb * SEQ;
  const int q0 = qt * 64;

  __shared__ bf16 sQ[64 * 64];
  __shared__ bf16 sK[2][64 * 64];
  __shared__ bf16 sV[2][80 * 64];   // rows 0..63 V^T tile; row 64 = ones, 65..79 = 0
  __shared__ bf16 sP[4][16 * 64];   // per wave, swizzled

  for (int idx = tid; idx < 16 * 64; idx += 256) {
    const bf16 v = (idx < 64) ? (bf16)1.f : (bf16)0.f;
    sV[0][64 * 64 + idx] = v;
    sV[1][64 * 64 + idx] = v;
  }

  const int srow = tid >> 3;          // 0..31
  const int g = tid & 7;
  const int gs = ((g ^ (srow & 7)) * 8);   // pre-swizzled source granule
  {
    const bf16* Qg = qkv + (tokBase + q0 + srow) * 2304 + h * 64;
    GLDS16(Qg + gs, sQ + srow * 64 + g * 8);
    GLDS16(Qg + (size_t)32 * 2304 + gs, sQ + (32 + srow) * 64 + g * 8);
  }
  __syncthreads();   // drains Q loads, publishes ones rows
  const int l15 = lane & 15, hi = lane >> 4;
  const int ksw = (l15 & 7) << 3;
  bf16x8 qf[2];
  {
    const int qrow = wave * 16 + l15;
    const int qsw = (qrow & 7) << 3;
    #pragma unroll
    for (int ks = 0; ks < 2; ++ks)
      qf[ks] = *(const bf16x8*)(sQ + qrow * 64 + ((hi * 8 + ks * 32) ^ qsw));
  }

  f32x4 o[5] = {};
  float mrun[4];
  #pragma unroll
  for (int r = 0; r < 4; ++r) mrun[r] = -1e30f;

  const bf16* Kbase = qkv + tokBase * 2304 + 768 + h * 64;
  const bf16* Vbase = VT + (size_t)bh * (HD * SEQ);

  {
    const bf16* Kg = Kbase + (size_t)srow * 2304;
    GLDS16(Kg + gs, sK[0] + srow * 64 + g * 8);
    GLDS16(Kg + (size_t)32 * 2304 + gs, sK[0] + (32 + srow) * 64 + g * 8);
    const bf16* Vg = Vbase + (size_t)srow * SEQ;
    GLDS16(Vg + gs, sV[0] + srow * 64 + g * 8);
    GLDS16(Vg + (size_t)32 * SEQ + gs, sV[0] + (32 + srow) * 64 + g * 8);
  }

  for (int it = 0; it < SEQ / 64; ++it) {
    const int cur = it & 1;
    if (it + 1 < SEQ / 64) {
      const int kb = (it + 1) * 64;
      const bf16* Kg = Kbase + (size_t)(kb + srow) * 2304;
      GLDS16(Kg + gs, sK[cur ^ 1] + srow * 64 + g * 8);
      GLDS16(Kg + (size_t)32 * 2304 + gs, sK[cur ^ 1] + (32 + srow) * 64 + g * 8);
      const bf16* Vg = Vbase + (size_t)srow * SEQ + kb;
      GLDS16(Vg + gs, sV[cur ^ 1] + srow * 64 + g * 8);
      GLDS16(Vg + (size_t)32 * SEQ + gs, sV[cur ^ 1] + (32 + srow) * 64 + g * 8);
      asm volatile("s_waitcnt vmcnt(4)" ::: "memory");
    } else {
      asm volatile("s_waitcnt vmcnt(0)" ::: "memory");
    }
    BARRIER();
    // S = Q K^T  (16 x 64 per wave)
    f32x4 s[4];
    __builtin_amdgcn_s_setprio(1);
    #pragma unroll
    for (int nj = 0; nj < 4; ++nj) {
      s[nj] = (f32x4){0.f, 0.f, 0.f, 0.f};
      #pragma unroll
      for (int ks = 0; ks < 2; ++ks) {
        bf16x8 kf = *(const bf16x8*)(sK[cur] + (nj * 16 + l15) * 64 + ((hi * 8 + ks * 32) ^ ksw));
        s[nj] = __builtin_amdgcn_mfma_f32_16x16x32_bf16(qf[ks], kf, s[nj], 0, 0, 0);
      }
    }
    __builtin_amdgcn_s_setprio(0);
    // online softmax; scale = 1/8 — max tree only (sum via ones-MFMA)
    float tmax[4];
    #pragma unroll
    for (int r = 0; r < 4; ++r) {
      float m = fmaxf(fmaxf(s[0][r], s[1][r]), fmaxf(s[2][r], s[3][r]));
      tmax[r] = m * 0.125f;
    }
    #pragma unroll
    for (int r = 0; r < 4; ++r) {
      #pragma unroll
      for (int mm = 1; mm < 16; mm <<= 1) tmax[r] = fmaxf(tmax[r], __shfl_xor(tmax[r], mm));
    }
    // exact defer: if no row's tile-max exceeds the running max, alpha == 1
    bool need = false;
    #pragma unroll
    for (int r = 0; r < 4; ++r) need |= (tmax[r] > mrun[r]);
    if (__any(need)) {
      float alpha[4];
      #pragma unroll
      for (int r = 0; r < 4; ++r) {
        const float mnew = fmaxf(mrun[r], tmax[r]);
        alpha[r] = __expf(mrun[r] - mnew);
        mrun[r] = mnew;
      }
      #pragma unroll
      for (int nj = 0; nj < 5; ++nj)
        #pragma unroll
        for (int r = 0; r < 4; ++r)
          o[nj][r] *= alpha[r];
    }
    float p[4][4];
    #pragma unroll
    for (int r = 0; r < 4; ++r)
      #pragma unroll
      for (int nj = 0; nj < 4; ++nj)
        p[nj][r] = __expf(s[nj][r] * 0.125f - mrun[r]);
    // P -> LDS (per-wave, swizzled; intra-wave DS ordering gives visibility)
    bf16* Pw = sP[wave];
    #pragma unroll
    for (int r = 0; r < 4; ++r) {
      const int prow = hi * 4 + r;
      const int psw = (prow & 7) << 3;
      #pragma unroll
      for (int nj = 0; nj < 4; ++nj)
        Pw[prow * 64 + ((nj * 16 + l15) ^ psw)] = (bf16)p[nj][r];
    }
    // O += P V  (nj = 4 accumulates the row-sum l via the ones row)
    __builtin_amdgcn_s_setprio(1);
    #pragma unroll
    for (int ks = 0; ks < 2; ++ks) {
      bf16x8 pa = *(const bf16x8*)(Pw + l15 * 64 + ((hi * 8 + ks * 32) ^ ksw));
      #pragma unroll
      for (int nj = 0; nj < 5; ++nj) {
        bf16x8 vb = *(const bf16x8*)(sV[cur] + (nj * 16 + l15) * 64 + ((hi * 8 + ks * 32) ^ ksw));
        o[nj] = __builtin_amdgcn_mfma_f32_16x16x32_bf16(pa, vb, o[nj], 0, 0, 0);
      }
    }
    __builtin_amdgcn_s_setprio(0);
    BARRIER();
  }
  #pragma unroll
  for (int r = 0; r < 4; ++r) {
    const float lsum = __shfl(o[4][r], hi << 4, 64);   // lane (hi,l15=0) holds l
    const float inv = 1.f / lsum;
    const size_t row = tokBase + q0 + wave * 16 + hi * 4 + r;
    bf16* orow = out + row * EMBED + h * 64;
    #pragma unroll
    for (int nj = 0; nj < 4; ++nj)
      orow[nj * 16 + l15] = (bf16)(o[nj][r] * inv);
  }
}

// -------------------------------------------------------------- combine ----
// out[t, n*192+c] = sum_m Hres[n][m]*xs[t, m*192+c] + Hpost[n]*t_mean[t,c]
// TWO=1: transform output = t + t2 (split-K partials).
template <int TWO>
__global__ void combine_kernel(const float* __restrict__ xs, const float* __restrict__ t,
                               const float* __restrict__ t2,
                               const float* __restrict__ Hres, const float* __restrict__ Hpost,
                               float* __restrict__ outp) {
  const int idx = blockIdx.x * 256 + threadIdx.x;
  if (idx >= TOKENS * CHUNK) return;
  const int tok = idx / CHUNK;
  const int c = idx - tok * CHUNK;
  const float* xr = xs + (size_t)tok * EMBED + c;
  const float* tr = t + (size_t)tok * EMBED + c;
  const float x0 = xr[0], x1 = xr[CHUNK], x2 = xr[2 * CHUNK], x3 = xr[3 * CHUNK];
  float tm = tr[0] + tr[CHUNK] + tr[2 * CHUNK] + tr[3 * CHUNK];
  if (TWO) {
    const float* t2r = t2 + (size_t)tok * EMBED + c;
    tm += t2r[0] + t2r[CHUNK] + t2r[2 * CHUNK] + t2r[3 * CHUNK];
  }
  tm *= 0.25f;
  #pragma unroll
  for (int n = 0; n < 4; ++n) {
    const float v = Hres[4*n+0]*x0 + Hres[4*n+1]*x1 + Hres[4*n+2]*x2 + Hres[4*n+3]*x3
                  + Hpost[n] * tm;
    outp[(size_t)tok * EMBED + n * CHUNK + c] = v;
  }
}

// ---------------------------------------------------------------- launch ---
extern "C" void kernel_launch(void* const* d_in, const int* in_sizes, int n_in,
                              void* d_out, int out_size, void* d_ws, size_t ws_size,
                              hipStream_t stream) {
  const float* x       = (const float*)d_in[0];
  const float* ln1_g   = (const float*)d_in[1];
  const float* ln1_b   = (const float*)d_in[2];
  const float* ln2_g   = (const float*)d_in[3];
  const float* ln2_b   = (const float*)d_in[4];
  const float* qkv_w   = (const float*)d_in[5];
  const float* qkv_b   = (const float*)d_in[6];
  const float* proj_w  = (const float*)d_in[7];
  const float* proj_b  = (const float*)d_in[8];
  const float* fc1_w   = (const float*)d_in[9];
  const float* fc1_b   = (const float*)d_in[10];
  const float* fc2_w   = (const float*)d_in[11];
  const float* fc2_b   = (const float*)d_in[12];
  const float* a_hres  = (const float*)d_in[13];
  const float* a_hpre  = (const float*)d_in[14];
  const float* a_hpost = (const float*)d_in[15];
  const float* m_hres  = (const float*)d_in[16];
  const float* m_hpre  = (const float*)d_in[17];
  const float* m_hpost = (const float*)d_in[18];

  char* ws = (char*)d_ws;
  float* HS = (float*)(ws);                                  // 48 floats
  bf16* Wq  = (bf16*)(ws + 1024);                            // 2304x768
  bf16* Wp  = (bf16*)(ws + 1024 + 3538944);                  // 768x768
  bf16* W1  = (bf16*)(ws + 1024 + 3538944 + 1179648);        // 3072x768
  bf16* W2  = (bf16*)(ws + 1024 + 3538944 + 1179648 + 4718592); // 768x3072
  bf16* LN  = (bf16*)(ws + 14156800);                        // 8192x768 bf16
  float* T  = (float*)(ws + 26739712);                       // 8192x768 f32
  float* X2 = (float*)(ws + 51905536);                       // 8192x768 f32
  bf16* QKV = (bf16*)(ws + 77071360);                        // 8192x2304 bf16
  bf16* AO  = (bf16*)(ws + 114820096);                       // 8192x768 bf16
  bf16* Hm  = (bf16*)(ws + 77071360);                        // 8192x3072 (overlays QKV+AO)
  bf16* VT  = LN;   // 96x64x1024 bf16 — overlays LN (dead after qkv GEMM)
  float* PT = (float*)(ws + 127403008);                      // 8192x768 f32 (fc2 split-K partial)
  const bool haveP = ws_size >= (size_t)127403008 + (size_t)TOKENS * EMBED * 4;

  hprep_kernel<<<1, 64, 0, stream>>>(a_hres, a_hpre, a_hpost, m_hres, m_hpre, m_hpost, HS);
  cvt_kernel<<<1024, 256, 0, stream>>>(qkv_w, Wq, 2304 * 768 / 4);
  cvt_kernel<<<1024, 256, 0, stream>>>(proj_w, Wp, 768 * 768 / 4);
  cvt_kernel<<<1024, 256, 0, stream>>>(fc1_w, W1, 3072 * 768 / 4);
  cvt_kernel<<<1024, 256, 0, stream>>>(fc2_w, W2, 768 * 3072 / 4);

  // ---- block 1: attention mhc ----
  preln_kernel<<<TOKENS, 256, 0, stream>>>(x, HS + 16, ln1_g, ln1_b, LN);
  gemm_bt<0, 0, 1><<<dim3(2304 / 128, TOKENS / 128), 256, 0, stream>>>(
      LN, Wq, qkv_b, QKV, nullptr, TOKENS, 2304, 768);
  vt_kernel<<<dim3(16, 96), 256, 0, stream>>>(QKV, VT);
  attn_kernel<<<1536, 256, 0, stream>>>(QKV, VT, AO);
  gemm_bt<0, 1, 1><<<dim3(768 / 128, TOKENS / 128), 256, 0, stream>>>(
      AO, Wp, proj_b, T, nullptr, TOKENS, 768, 768);
  combine_kernel<0><<<(TOKENS * CHUNK + 255) / 256, 256, 0, stream>>>(
      x, T, nullptr, HS + 0, HS + 20, X2);

  // ---- block 2: MLP mhc ----
  preln_kernel<<<TOKENS, 256, 0, stream>>>(X2, HS + 24 + 16, ln2_g, ln2_b, LN);
  gemm_bt<1, 0, 1><<<dim3(3072 / 128, TOKENS / 128), 256, 0, stream>>>(
      LN, W1, fc1_b, Hm, nullptr, TOKENS, 3072, 768);
  if (haveP) {
    gemm_bt<0, 1, 2><<<dim3(768 / 128, TOKENS / 128, 2), 256, 0, stream>>>(
        Hm, W2, fc2_b, T, PT, TOKENS, 768, 3072);
    combine_kernel<1><<<(TOKENS * CHUNK + 255) / 256, 256, 0, stream>>>(
        X2, T, PT, HS + 24, HS + 24 + 20, (float*)d_out);
  } else {
    gemm_bt<0, 1, 1><<<dim3(768 / 128, TOKENS / 128), 256, 0, stream>>>(
        Hm, W2, fc2_b, T, nullptr, TOKENS, 768, 3072);
    combine_kernel<0><<<(TOKENS * CHUNK + 255) / 256, 256, 0, stream>>>(
        X2, T, nullptr, HS + 24, HS + 24 + 20, (float*)d_out);
  }
}

// Round 9
// 344.139 us; speedup vs baseline: 1.1853x; 1.1853x over previous
//
#include <hip/hip_runtime.h>
#include <hip/hip_bf16.h>
#include <cstdint>
#include <cstddef>

#define EMBED 768
#define STREAMS 4
#define CHUNK 192          // EMBED / STREAMS
#define HEADS 12
#define HD 64
#define SEQ 1024
#define BATCH 8
#define TOKENS (BATCH * SEQ)   // 8192
#define MLPH 3072

typedef __bf16 bf16;
typedef __bf16 bf16x4 __attribute__((ext_vector_type(4)));
typedef __bf16 bf16x8 __attribute__((ext_vector_type(8)));
typedef float f32x4 __attribute__((ext_vector_type(4)));
typedef float f32x16 __attribute__((ext_vector_type(16)));

// async global->LDS, 16B per lane; LDS dest must be linear in lane order
#define GLDS16(gp, lp)                                                        \
  __builtin_amdgcn_global_load_lds(                                           \
      (const __attribute__((address_space(1))) void*)(gp),                    \
      (__attribute__((address_space(3))) void*)(lp), 16, 0, 0)

// raw barrier (no vmcnt(0) drain) with compiler memory fences on both sides
#define BARRIER() do { asm volatile("" ::: "memory");                         \
  __builtin_amdgcn_s_barrier(); asm volatile("" ::: "memory"); } while (0)

// ---------------------------------------------------------------- hprep ----
__global__ void hprep_kernel(const float* ar, const float* ap, const float* ao,
                             const float* mr, const float* mp, const float* mo,
                             float* HS) {
  if (threadIdx.x != 0) return;
  const float* L[2] = {ar, mr};
  const float* P[2] = {ap, mp};
  const float* O[2] = {ao, mo};
  for (int s = 0; s < 2; ++s) {
    float A[16];
    for (int i = 0; i < 16; ++i) A[i] = expf(L[s][i]);
    for (int it = 0; it < 20; ++it) {
      for (int r = 0; r < 4; ++r) {
        float rs = A[4*r] + A[4*r+1] + A[4*r+2] + A[4*r+3] + 1e-8f;
        for (int c = 0; c < 4; ++c) A[4*r+c] /= rs;
      }
      for (int c = 0; c < 4; ++c) {
        float cs = A[c] + A[4+c] + A[8+c] + A[12+c] + 1e-8f;
        for (int r = 0; r < 4; ++r) A[4*r+c] /= cs;
      }
    }
    float* dst = HS + s * 24;
    for (int i = 0; i < 16; ++i) dst[i] = A[i];
    {
      float m = fmaxf(fmaxf(P[s][0], P[s][1]), fmaxf(P[s][2], P[s][3]));
      float e[4], t = 0.f;
      for (int i = 0; i < 4; ++i) { e[i] = expf(P[s][i] - m); t += e[i]; }
      for (int i = 0; i < 4; ++i) dst[16 + i] = e[i] / t;
    }
    {
      float m = fmaxf(fmaxf(O[s][0], O[s][1]), fmaxf(O[s][2], O[s][3]));
      float e[4], t = 0.f;
      for (int i = 0; i < 4; ++i) { e[i] = expf(O[s][i] - m); t += e[i]; }
      for (int i = 0; i < 4; ++i) dst[20 + i] = e[i] / t;
    }
  }
}

// ------------------------------------------------------------------ cvt ----
__global__ void cvt_kernel(const float* __restrict__ in, bf16* __restrict__ out, int n4) {
  int i = blockIdx.x * 256 + threadIdx.x;
  const int st = gridDim.x * 256;
  for (; i < n4; i += st) {
    const float4 v = ((const float4*)in)[i];
    bf16x4 o = {(bf16)v.x, (bf16)v.y, (bf16)v.z, (bf16)v.w};
    *(bf16x4*)(out + (size_t)i * 4) = o;
  }
}

// ---------------------------------------------------------------- preln ----
__global__ __launch_bounds__(256) void preln_kernel(
    const float* __restrict__ x, const float* __restrict__ H,
    const float* __restrict__ g, const float* __restrict__ b,
    bf16* __restrict__ out) {
  const int t = blockIdx.x;
  const float* xr = x + (size_t)t * EMBED;
  __shared__ float s[CHUNK];
  __shared__ float part[8];
  __shared__ float red[2];
  const int tid = threadIdx.x;
  float sv = 0.f;
  if (tid < CHUNK) {
    sv = H[0]*xr[tid] + H[1]*xr[CHUNK+tid] + H[2]*xr[2*CHUNK+tid] + H[3]*xr[3*CHUNK+tid];
    s[tid] = sv;
  }
  float sum = sv, sq = sv * sv;
  #pragma unroll
  for (int m = 32; m > 0; m >>= 1) {
    sum += __shfl_down(sum, m);
    sq  += __shfl_down(sq, m);
  }
  if ((tid & 63) == 0) { part[tid >> 6] = sum; part[4 + (tid >> 6)] = sq; }
  __syncthreads();
  if (tid == 0) {
    float S = part[0] + part[1] + part[2] + part[3];
    float Q = part[4] + part[5] + part[6] + part[7];
    float mu = S * (1.f / CHUNK);
    float var = Q * (1.f / CHUNK) - mu * mu;
    red[0] = mu;
    red[1] = rsqrtf(var + 1e-5f);
  }
  __syncthreads();
  const float mu = red[0], rs = red[1];
  bf16* orow = out + (size_t)t * EMBED;
  #pragma unroll
  for (int r = 0; r < 3; ++r) {
    const int d = tid + r * 256;
    const float v = (s[d % CHUNK] - mu) * rs * g[d] + b[d];
    orow[d] = (bf16)v;
  }
}

// ----------------------------------------------------------------- gemm ----
// C[m,n] = sum_k A[m,k]*B[n,k] + bias[n]; bf16 row-major A (MxK), B (NxK).
// 128x128 tile, BK=32, 32x32x16 MFMA, 3-buffer LDS pipeline (2-deep
// prefetch, vmcnt(8) steady state). No setprio (lockstep 4-wave block —
// T5 is null-to-negative here, m190). T1 XCD block swizzle (nwg % 8 == 0).
// KSPLIT=2: blockIdx.z halves K; z=1 writes partial to C1 (no bias).
// All outputs bf16. LDS swizzle: granule ^= (row>>1)&3 (bank period of a
// 64B row = 2 rows); staging pre-swizzles global source, dest linear.
template <int GELU, int KSPLIT>
__global__ __launch_bounds__(256, 2) void gemm_bt(
    const bf16* __restrict__ A, const bf16* __restrict__ B,
    const float* __restrict__ bias, bf16* __restrict__ C0,
    bf16* __restrict__ C1, int M, int N, int K) {
  constexpr int BM = 128, BN = 128, BK = 32;
  __shared__ bf16 sA[3][BM * BK];
  __shared__ bf16 sB[3][BN * BK];
  const int tid  = threadIdx.x;
  const int lane = tid & 63;
  const int nwg = gridDim.x * gridDim.y;
  int Lw = blockIdx.y * gridDim.x + blockIdx.x;
  Lw = (Lw & 7) * (nwg >> 3) + (Lw >> 3);
  const int bm = (Lw / gridDim.x) * BM;
  const int bn = (Lw % gridDim.x) * BN;
  const int wave = tid >> 6;
  const int wr = (wave >> 1) * 64;
  const int wc = (wave & 1) * 64;
  f32x16 acc[2][2] = {};
  const int tr = tid >> 2;
  const int gt = tid & 3;
  const int gsw = (gt ^ ((tr >> 1) & 3)) * 8;   // inverse-swizzled source granule
  const int kbeg = (KSPLIT > 1) ? blockIdx.z * (K / KSPLIT) : 0;
  const bf16* Ag = A + (size_t)(bm + tr) * K + kbeg + gsw;
  const bf16* Bg = B + (size_t)(bn + tr) * K + kbeg + gsw;
  const int lofs = tr * BK + gt * 8;
  const int r31 = lane & 31, rh = lane >> 5;
  const int asw = (r31 >> 1) & 3;               // read-side swizzle (row bits 2:1)
  const int nst = K / KSPLIT / BK;
#define STAGE(buf, t)                                                         \
  do { const int bk_ = (t) * BK;                                              \
    GLDS16(Ag + bk_, sA[buf] + lofs);                                         \
    GLDS16(Ag + (size_t)64 * K + bk_, sA[buf] + lofs + 64 * BK);              \
    GLDS16(Bg + bk_, sB[buf] + lofs);                                         \
    GLDS16(Bg + (size_t)64 * K + bk_, sB[buf] + lofs + 64 * BK);              \
  } while (0)
  STAGE(0, 0);
  STAGE(1, 1);
  int cur = 0;
  for (int t = 0; t < nst; ++t) {
    if (t + 2 < nst) {
      const int nb = cur + 2 >= 3 ? cur - 1 : cur + 2;
      STAGE(nb, t + 2);
      asm volatile("s_waitcnt vmcnt(8)" ::: "memory");
    } else if (t + 1 < nst) {
      asm volatile("s_waitcnt vmcnt(4)" ::: "memory");
    } else {
      asm volatile("s_waitcnt vmcnt(0)" ::: "memory");
    }
    BARRIER();
    bf16x8 af[2][2], bfr[2][2];
    #pragma unroll
    for (int ks = 0; ks < 2; ++ks) {
      const int pos = ((ks * 2 + rh) ^ asw) * 8;
      #pragma unroll
      for (int i = 0; i < 2; ++i) {
        af[i][ks]  = *(const bf16x8*)(sA[cur] + (wr + i * 32 + r31) * BK + pos);
        bfr[i][ks] = *(const bf16x8*)(sB[cur] + (wc + i * 32 + r31) * BK + pos);
      }
    }
    #pragma unroll
    for (int ks = 0; ks < 2; ++ks)
      #pragma unroll
      for (int i = 0; i < 2; ++i)
        #pragma unroll
        for (int j = 0; j < 2; ++j)
          acc[i][j] = __builtin_amdgcn_mfma_f32_32x32x16_bf16(af[i][ks], bfr[j][ks], acc[i][j], 0, 0, 0);
    BARRIER();
    cur = cur == 2 ? 0 : cur + 1;
  }
#undef STAGE
  // C/D 32x32 layout: col = lane&31, row = (reg&3) + 8*(reg>>2) + 4*(lane>>5)
  const bool second = (KSPLIT > 1) && (blockIdx.z != 0);
  bf16* Co = second ? C1 : C0;
  #pragma unroll
  for (int j = 0; j < 2; ++j) {
    const int col = bn + wc + j * 32 + r31;
    const float bv = second ? 0.f : bias[col];
    #pragma unroll
    for (int i = 0; i < 2; ++i) {
      const int row0 = bm + wr + i * 32 + 4 * rh;
      #pragma unroll
      for (int reg = 0; reg < 16; ++reg) {
        const int row = row0 + (reg & 3) + 8 * (reg >> 2);
        float v = acc[i][j][reg] + bv;
        if (GELU) {
          // tanh-approx GELU via hw exp (clamped against overflow)
          float u = 0.7978845608f * (v + 0.044715f * v * v * v);
          u = fmaxf(fminf(u, 15.f), -15.f);
          const float e = __expf(-2.f * u);
          v = v / (1.f + e);             // 0.5*v*(1+tanh(u)) == v/(1+e^{-2u})
        }
        Co[(size_t)row * N + col] = (bf16)v;
      }
    }
  }
}

// ------------------------------------------------------------------- vt ----
// VT[bh][hd][tok] = qkv[bb*1024+tok][1536 + h*64 + hd]; swizzled LDS stage.
__global__ __launch_bounds__(256) void vt_kernel(const bf16* __restrict__ qkv,
                                                 bf16* __restrict__ VT) {
  const int tt = blockIdx.x;   // 16 tok tiles of 64
  const int bh = blockIdx.y;   // 96
  const int bb = bh / HEADS;
  const int h = bh - bb * HEADS;
  __shared__ bf16 sT[64 * 64];
  const int t = threadIdx.x;
  const int srow = t >> 3;            // 0..31 (tok within half-tile)
  const int g = t & 7;                // 16B granule
  const int gs = ((g ^ (srow & 7)) * 8);
  const bf16* Vg = qkv + ((size_t)(bb * SEQ + tt * 64 + srow)) * 2304 + 1536 + h * 64;
  GLDS16(Vg + gs, sT + srow * 64 + g * 8);
  GLDS16(Vg + (size_t)32 * 2304 + gs, sT + (32 + srow) * 64 + g * 8);
  __syncthreads();
  const int hd = t >> 2;
  const int tg = (t & 3) * 16;
  bf16 tmp[16];
  #pragma unroll
  for (int j = 0; j < 16; ++j) {
    const int tok = tg + j;
    tmp[j] = sT[tok * 64 + (hd ^ ((tok & 7) << 3))];
  }
  bf16* op = VT + (size_t)bh * (HD * SEQ) + (size_t)hd * SEQ + tt * 64 + tg;
  *(bf16x8*)(op) = *(const bf16x8*)(tmp);
  *(bf16x8*)(op + 8) = *(const bf16x8*)(tmp + 8);
}

// ----------------------------------------------------------------- attn ----
// Flash attention, swizzled LDS, double-buffered K/V, row-sum via ones-row
// MFMA, exact defer-rescale, bh-major XCD-chunked mapping, setprio (T5 —
// attn blocks are at independent phases; m191 regime).
__global__ __launch_bounds__(256) void attn_kernel(
    const bf16* __restrict__ qkv, const bf16* __restrict__ VT,
    bf16* __restrict__ out) {
  const int lin = blockIdx.x;
  const int qt = (lin >> 3) & 15;
  const int bh = (lin & 7) + 8 * (lin >> 7);
  const int bb = bh / HEADS;
  const int h = bh - bb * HEADS;
  const int tid = threadIdx.x;
  const int lane = tid & 63;
  const int wave = tid >> 6;
  const size_t tokBase = (size_t)bb * SEQ;
  const int q0 = qt * 64;

  __shared__ bf16 sQ[64 * 64];
  __shared__ bf16 sK[2][64 * 64];
  __shared__ bf16 sV[2][80 * 64];   // rows 0..63 V^T tile; row 64 = ones, 65..79 = 0
  __shared__ bf16 sP[4][16 * 64];   // per wave, swizzled

  for (int idx = tid; idx < 16 * 64; idx += 256) {
    const bf16 v = (idx < 64) ? (bf16)1.f : (bf16)0.f;
    sV[0][64 * 64 + idx] = v;
    sV[1][64 * 64 + idx] = v;
  }

  const int srow = tid >> 3;          // 0..31
  const int g = tid & 7;
  const int gs = ((g ^ (srow & 7)) * 8);   // pre-swizzled source granule
  {
    const bf16* Qg = qkv + (tokBase + q0 + srow) * 2304 + h * 64;
    GLDS16(Qg + gs, sQ + srow * 64 + g * 8);
    GLDS16(Qg + (size_t)32 * 2304 + gs, sQ + (32 + srow) * 64 + g * 8);
  }
  __syncthreads();   // drains Q loads, publishes ones rows
  const int l15 = lane & 15, hi = lane >> 4;
  const int ksw = (l15 & 7) << 3;
  bf16x8 qf[2];
  {
    const int qrow = wave * 16 + l15;
    const int qsw = (qrow & 7) << 3;
    #pragma unroll
    for (int ks = 0; ks < 2; ++ks)
      qf[ks] = *(const bf16x8*)(sQ + qrow * 64 + ((hi * 8 + ks * 32) ^ qsw));
  }

  f32x4 o[5] = {};
  float mrun[4];
  #pragma unroll
  for (int r = 0; r < 4; ++r) mrun[r] = -1e30f;

  const bf16* Kbase = qkv + tokBase * 2304 + 768 + h * 64;
  const bf16* Vbase = VT + (size_t)bh * (HD * SEQ);

  {
    const bf16* Kg = Kbase + (size_t)srow * 2304;
    GLDS16(Kg + gs, sK[0] + srow * 64 + g * 8);
    GLDS16(Kg + (size_t)32 * 2304 + gs, sK[0] + (32 + srow) * 64 + g * 8);
    const bf16* Vg = Vbase + (size_t)srow * SEQ;
    GLDS16(Vg + gs, sV[0] + srow * 64 + g * 8);
    GLDS16(Vg + (size_t)32 * SEQ + gs, sV[0] + (32 + srow) * 64 + g * 8);
  }

  for (int it = 0; it < SEQ / 64; ++it) {
    const int cur = it & 1;
    if (it + 1 < SEQ / 64) {
      const int kb = (it + 1) * 64;
      const bf16* Kg = Kbase + (size_t)(kb + srow) * 2304;
      GLDS16(Kg + gs, sK[cur ^ 1] + srow * 64 + g * 8);
      GLDS16(Kg + (size_t)32 * 2304 + gs, sK[cur ^ 1] + (32 + srow) * 64 + g * 8);
      const bf16* Vg = Vbase + (size_t)srow * SEQ + kb;
      GLDS16(Vg + gs, sV[cur ^ 1] + srow * 64 + g * 8);
      GLDS16(Vg + (size_t)32 * SEQ + gs, sV[cur ^ 1] + (32 + srow) * 64 + g * 8);
      asm volatile("s_waitcnt vmcnt(4)" ::: "memory");
    } else {
      asm volatile("s_waitcnt vmcnt(0)" ::: "memory");
    }
    BARRIER();
    // S = Q K^T  (16 x 64 per wave)
    f32x4 s[4];
    __builtin_amdgcn_s_setprio(1);
    #pragma unroll
    for (int nj = 0; nj < 4; ++nj) {
      s[nj] = (f32x4){0.f, 0.f, 0.f, 0.f};
      #pragma unroll
      for (int ks = 0; ks < 2; ++ks) {
        bf16x8 kf = *(const bf16x8*)(sK[cur] + (nj * 16 + l15) * 64 + ((hi * 8 + ks * 32) ^ ksw));
        s[nj] = __builtin_amdgcn_mfma_f32_16x16x32_bf16(qf[ks], kf, s[nj], 0, 0, 0);
      }
    }
    __builtin_amdgcn_s_setprio(0);
    // online softmax; scale = 1/8 — max tree only (sum via ones-MFMA)
    float tmax[4];
    #pragma unroll
    for (int r = 0; r < 4; ++r) {
      float m = fmaxf(fmaxf(s[0][r], s[1][r]), fmaxf(s[2][r], s[3][r]));
      tmax[r] = m * 0.125f;
    }
    #pragma unroll
    for (int r = 0; r < 4; ++r) {
      #pragma unroll
      for (int mm = 1; mm < 16; mm <<= 1) tmax[r] = fmaxf(tmax[r], __shfl_xor(tmax[r], mm));
    }
    // exact defer: if no row's tile-max exceeds the running max, alpha == 1
    bool need = false;
    #pragma unroll
    for (int r = 0; r < 4; ++r) need |= (tmax[r] > mrun[r]);
    if (__any(need)) {
      float alpha[4];
      #pragma unroll
      for (int r = 0; r < 4; ++r) {
        const float mnew = fmaxf(mrun[r], tmax[r]);
        alpha[r] = __expf(mrun[r] - mnew);
        mrun[r] = mnew;
      }
      #pragma unroll
      for (int nj = 0; nj < 5; ++nj)
        #pragma unroll
        for (int r = 0; r < 4; ++r)
          o[nj][r] *= alpha[r];
    }
    float p[4][4];
    #pragma unroll
    for (int r = 0; r < 4; ++r)
      #pragma unroll
      for (int nj = 0; nj < 4; ++nj)
        p[nj][r] = __expf(s[nj][r] * 0.125f - mrun[r]);
    // P -> LDS (per-wave, swizzled; intra-wave DS ordering gives visibility)
    bf16* Pw = sP[wave];
    #pragma unroll
    for (int r = 0; r < 4; ++r) {
      const int prow = hi * 4 + r;
      const int psw = (prow & 7) << 3;
      #pragma unroll
      for (int nj = 0; nj < 4; ++nj)
        Pw[prow * 64 + ((nj * 16 + l15) ^ psw)] = (bf16)p[nj][r];
    }
    // O += P V  (nj = 4 accumulates the row-sum l via the ones row)
    __builtin_amdgcn_s_setprio(1);
    #pragma unroll
    for (int ks = 0; ks < 2; ++ks) {
      bf16x8 pa = *(const bf16x8*)(Pw + l15 * 64 + ((hi * 8 + ks * 32) ^ ksw));
      #pragma unroll
      for (int nj = 0; nj < 5; ++nj) {
        bf16x8 vb = *(const bf16x8*)(sV[cur] + (nj * 16 + l15) * 64 + ((hi * 8 + ks * 32) ^ ksw));
        o[nj] = __builtin_amdgcn_mfma_f32_16x16x32_bf16(pa, vb, o[nj], 0, 0, 0);
      }
    }
    __builtin_amdgcn_s_setprio(0);
    BARRIER();
  }
  #pragma unroll
  for (int r = 0; r < 4; ++r) {
    const float lsum = __shfl(o[4][r], hi << 4, 64);   // lane (hi,l15=0) holds l
    const float inv = 1.f / lsum;
    const size_t row = tokBase + q0 + wave * 16 + hi * 4 + r;
    bf16* orow = out + row * EMBED + h * 64;
    #pragma unroll
    for (int nj = 0; nj < 4; ++nj)
      orow[nj * 16 + l15] = (bf16)(o[nj][r] * inv);
  }
}

// -------------------------------------------------------- combine+preln ----
// Fused block-1 exit / block-2 entry. Per token t:
//   x2[n][c] = sum_m Hres[n][m]*x[t,m*192+c] + Hpost[n]*t_mean[c]   -> X2 (f32)
//   s2[c]    = sum_n Hpre2[n]*x2[n][c];  LN over s2 -> LN (bf16, tiled x4)
__global__ __launch_bounds__(256) void combine_preln_kernel(
    const float* __restrict__ x, const bf16* __restrict__ t,
    const float* __restrict__ Hres, const float* __restrict__ Hpost,
    const float* __restrict__ Hpre2,
    const float* __restrict__ g2, const float* __restrict__ b2,
    float* __restrict__ X2, bf16* __restrict__ LN) {
  const int tok = blockIdx.x;
  const int tid = threadIdx.x;
  __shared__ float s[CHUNK];
  __shared__ float part[8];
  __shared__ float red[2];
  float sv = 0.f;
  if (tid < CHUNK) {
    const float* xr = x + (size_t)tok * EMBED + tid;
    const bf16* tr = t + (size_t)tok * EMBED + tid;
    const float x0 = xr[0], x1 = xr[CHUNK], x2v = xr[2 * CHUNK], x3 = xr[3 * CHUNK];
    const float tm = 0.25f * ((float)tr[0] + (float)tr[CHUNK] +
                              (float)tr[2 * CHUNK] + (float)tr[3 * CHUNK]);
    float* orow = X2 + (size_t)tok * EMBED + tid;
    #pragma unroll
    for (int n = 0; n < 4; ++n) {
      const float v = Hres[4*n+0]*x0 + Hres[4*n+1]*x1 + Hres[4*n+2]*x2v + Hres[4*n+3]*x3
                    + Hpost[n] * tm;
      orow[n * CHUNK] = v;
      sv += Hpre2[n] * v;
    }
    s[tid] = sv;
  }
  float sum = sv, sq = sv * sv;
  #pragma unroll
  for (int m = 32; m > 0; m >>= 1) {
    sum += __shfl_down(sum, m);
    sq  += __shfl_down(sq, m);
  }
  if ((tid & 63) == 0) { part[tid >> 6] = sum; part[4 + (tid >> 6)] = sq; }
  __syncthreads();
  if (tid == 0) {
    float S = part[0] + part[1] + part[2] + part[3];
    float Q = part[4] + part[5] + part[6] + part[7];
    float mu = S * (1.f / CHUNK);
    float var = Q * (1.f / CHUNK) - mu * mu;
    red[0] = mu;
    red[1] = rsqrtf(var + 1e-5f);
  }
  __syncthreads();
  const float mu = red[0], rs = red[1];
  bf16* lrow = LN + (size_t)tok * EMBED;
  #pragma unroll
  for (int r = 0; r < 3; ++r) {
    const int d = tid + r * 256;
    lrow[d] = (bf16)((s[d % CHUNK] - mu) * rs * g2[d] + b2[d]);
  }
}

// -------------------------------------------------------------- combine ----
// Final combine (writes f32 d_out). TWO=1: transform = t + t2 (split-K).
template <int TWO>
__global__ void combine_kernel(const float* __restrict__ xs, const bf16* __restrict__ t,
                               const bf16* __restrict__ t2,
                               const float* __restrict__ Hres, const float* __restrict__ Hpost,
                               float* __restrict__ outp) {
  const int idx = blockIdx.x * 256 + threadIdx.x;
  if (idx >= TOKENS * CHUNK) return;
  const int tok = idx / CHUNK;
  const int c = idx - tok * CHUNK;
  const float* xr = xs + (size_t)tok * EMBED + c;
  const bf16* tr = t + (size_t)tok * EMBED + c;
  const float x0 = xr[0], x1 = xr[CHUNK], x2 = xr[2 * CHUNK], x3 = xr[3 * CHUNK];
  float tm = (float)tr[0] + (float)tr[CHUNK] + (float)tr[2 * CHUNK] + (float)tr[3 * CHUNK];
  if (TWO) {
    const bf16* t2r = t2 + (size_t)tok * EMBED + c;
    tm += (float)t2r[0] + (float)t2r[CHUNK] + (float)t2r[2 * CHUNK] + (float)t2r[3 * CHUNK];
  }
  tm *= 0.25f;
  #pragma unroll
  for (int n = 0; n < 4; ++n) {
    const float v = Hres[4*n+0]*x0 + Hres[4*n+1]*x1 + Hres[4*n+2]*x2 + Hres[4*n+3]*x3
                  + Hpost[n] * tm;
    outp[(size_t)tok * EMBED + n * CHUNK + c] = v;
  }
}

// ---------------------------------------------------------------- launch ---
extern "C" void kernel_launch(void* const* d_in, const int* in_sizes, int n_in,
                              void* d_out, int out_size, void* d_ws, size_t ws_size,
                              hipStream_t stream) {
  const float* x       = (const float*)d_in[0];
  const float* ln1_g   = (const float*)d_in[1];
  const float* ln1_b   = (const float*)d_in[2];
  const float* ln2_g   = (const float*)d_in[3];
  const float* ln2_b   = (const float*)d_in[4];
  const float* qkv_w   = (const float*)d_in[5];
  const float* qkv_b   = (const float*)d_in[6];
  const float* proj_w  = (const float*)d_in[7];
  const float* proj_b  = (const float*)d_in[8];
  const float* fc1_w   = (const float*)d_in[9];
  const float* fc1_b   = (const float*)d_in[10];
  const float* fc2_w   = (const float*)d_in[11];
  const float* fc2_b   = (const float*)d_in[12];
  const float* a_hres  = (const float*)d_in[13];
  const float* a_hpre  = (const float*)d_in[14];
  const float* a_hpost = (const float*)d_in[15];
  const float* m_hres  = (const float*)d_in[16];
  const float* m_hpre  = (const float*)d_in[17];
  const float* m_hpost = (const float*)d_in[18];

  char* ws = (char*)d_ws;
  float* HS = (float*)(ws);                                  // 48 floats
  bf16* Wq  = (bf16*)(ws + 1024);                            // 2304x768
  bf16* Wp  = (bf16*)(ws + 1024 + 3538944);                  // 768x768
  bf16* W1  = (bf16*)(ws + 1024 + 3538944 + 1179648);        // 3072x768
  bf16* W2  = (bf16*)(ws + 1024 + 3538944 + 1179648 + 4718592); // 768x3072
  bf16* LN  = (bf16*)(ws + 14156800);                        // 8192x768 bf16
  bf16* T   = (bf16*)(ws + 26739712);                        // 8192x768 bf16
  bf16* PT  = (bf16*)(ws + 39322624);                        // 8192x768 bf16 (split-K partial)
  float* X2 = (float*)(ws + 51905536);                       // 8192x768 f32
  bf16* QKV = (bf16*)(ws + 77071360);                        // 8192x2304 bf16
  bf16* AO  = (bf16*)(ws + 114820096);                       // 8192x768 bf16
  bf16* Hm  = (bf16*)(ws + 77071360);                        // 8192x3072 (overlays QKV+AO)
  bf16* VT  = LN;   // 96x64x1024 bf16 — overlays LN (dead after qkv GEMM)

  hprep_kernel<<<1, 64, 0, stream>>>(a_hres, a_hpre, a_hpost, m_hres, m_hpre, m_hpost, HS);
  cvt_kernel<<<1024, 256, 0, stream>>>(qkv_w, Wq, 2304 * 768 / 4);
  cvt_kernel<<<1024, 256, 0, stream>>>(proj_w, Wp, 768 * 768 / 4);
  cvt_kernel<<<1024, 256, 0, stream>>>(fc1_w, W1, 3072 * 768 / 4);
  cvt_kernel<<<1024, 256, 0, stream>>>(fc2_w, W2, 768 * 3072 / 4);

  // ---- block 1: attention mhc ----
  preln_kernel<<<TOKENS, 256, 0, stream>>>(x, HS + 16, ln1_g, ln1_b, LN);
  gemm_bt<0, 1><<<dim3(2304 / 128, TOKENS / 128), 256, 0, stream>>>(
      LN, Wq, qkv_b, QKV, nullptr, TOKENS, 2304, 768);
  vt_kernel<<<dim3(16, 96), 256, 0, stream>>>(QKV, VT);
  attn_kernel<<<1536, 256, 0, stream>>>(QKV, VT, AO);
  gemm_bt<0, 1><<<dim3(768 / 128, TOKENS / 128), 256, 0, stream>>>(
      AO, Wp, proj_b, T, nullptr, TOKENS, 768, 768);
  // fused: combine block-1 + preLN block-2 (writes X2 f32 + LN bf16)
  combine_preln_kernel<<<TOKENS, 256, 0, stream>>>(
      x, T, HS + 0, HS + 20, HS + 24 + 16, ln2_g, ln2_b, X2, LN);

  // ---- block 2: MLP mhc ----
  gemm_bt<1, 1><<<dim3(3072 / 128, TOKENS / 128), 256, 0, stream>>>(
      LN, W1, fc1_b, Hm, nullptr, TOKENS, 3072, 768);
  gemm_bt<0, 2><<<dim3(768 / 128, TOKENS / 128, 2), 256, 0, stream>>>(
      Hm, W2, fc2_b, T, PT, TOKENS, 768, 3072);
  combine_kernel<1><<<(TOKENS * CHUNK + 255) / 256, 256, 0, stream>>>(
      X2, T, PT, HS + 24, HS + 24 + 20, (float*)d_out);
}

// Round 10
// 323.065 us; speedup vs baseline: 1.2627x; 1.0652x over previous
//
#include <hip/hip_runtime.h>
#include <hip/hip_bf16.h>
#include <cstdint>
#include <cstddef>

#define EMBED 768
#define STREAMS 4
#define CHUNK 192          // EMBED / STREAMS
#define HEADS 12
#define HD 64
#define SEQ 1024
#define BATCH 8
#define TOKENS (BATCH * SEQ)   // 8192
#define MLPH 3072

typedef __bf16 bf16;
typedef __bf16 bf16x4 __attribute__((ext_vector_type(4)));
typedef __bf16 bf16x8 __attribute__((ext_vector_type(8)));
typedef float f32x4 __attribute__((ext_vector_type(4)));
typedef float f32x16 __attribute__((ext_vector_type(16)));

// async global->LDS, 16B per lane; LDS dest must be linear in lane order
#define GLDS16(gp, lp)                                                        \
  __builtin_amdgcn_global_load_lds(                                           \
      (const __attribute__((address_space(1))) void*)(gp),                    \
      (__attribute__((address_space(3))) void*)(lp), 16, 0, 0)

// raw barrier (no vmcnt(0) drain) with compiler memory fences on both sides
#define BARRIER() do { asm volatile("" ::: "memory");                         \
  __builtin_amdgcn_s_barrier(); asm volatile("" ::: "memory"); } while (0)

// ---------------------------------------------------------------- hprep ----
__global__ void hprep_kernel(const float* ar, const float* ap, const float* ao,
                             const float* mr, const float* mp, const float* mo,
                             float* HS) {
  if (threadIdx.x != 0) return;
  const float* L[2] = {ar, mr};
  const float* P[2] = {ap, mp};
  const float* O[2] = {ao, mo};
  for (int s = 0; s < 2; ++s) {
    float A[16];
    for (int i = 0; i < 16; ++i) A[i] = expf(L[s][i]);
    for (int it = 0; it < 20; ++it) {
      for (int r = 0; r < 4; ++r) {
        float rs = A[4*r] + A[4*r+1] + A[4*r+2] + A[4*r+3] + 1e-8f;
        for (int c = 0; c < 4; ++c) A[4*r+c] /= rs;
      }
      for (int c = 0; c < 4; ++c) {
        float cs = A[c] + A[4+c] + A[8+c] + A[12+c] + 1e-8f;
        for (int r = 0; r < 4; ++r) A[4*r+c] /= cs;
      }
    }
    float* dst = HS + s * 24;
    for (int i = 0; i < 16; ++i) dst[i] = A[i];
    {
      float m = fmaxf(fmaxf(P[s][0], P[s][1]), fmaxf(P[s][2], P[s][3]));
      float e[4], t = 0.f;
      for (int i = 0; i < 4; ++i) { e[i] = expf(P[s][i] - m); t += e[i]; }
      for (int i = 0; i < 4; ++i) dst[16 + i] = e[i] / t;
    }
    {
      float m = fmaxf(fmaxf(O[s][0], O[s][1]), fmaxf(O[s][2], O[s][3]));
      float e[4], t = 0.f;
      for (int i = 0; i < 4; ++i) { e[i] = expf(O[s][i] - m); t += e[i]; }
      for (int i = 0; i < 4; ++i) dst[20 + i] = e[i] / t;
    }
  }
}

// ------------------------------------------------------------------ cvt ----
__global__ void cvt_kernel(const float* __restrict__ in, bf16* __restrict__ out, int n4) {
  int i = blockIdx.x * 256 + threadIdx.x;
  const int st = gridDim.x * 256;
  for (; i < n4; i += st) {
    const float4 v = ((const float4*)in)[i];
    bf16x4 o = {(bf16)v.x, (bf16)v.y, (bf16)v.z, (bf16)v.w};
    *(bf16x4*)(out + (size_t)i * 4) = o;
  }
}

// ---------------------------------------------------------------- preln ----
__global__ __launch_bounds__(256) void preln_kernel(
    const float* __restrict__ x, const float* __restrict__ H,
    const float* __restrict__ g, const float* __restrict__ b,
    bf16* __restrict__ out) {
  const int t = blockIdx.x;
  const float* xr = x + (size_t)t * EMBED;
  __shared__ float s[CHUNK];
  __shared__ float part[8];
  __shared__ float red[2];
  const int tid = threadIdx.x;
  float sv = 0.f;
  if (tid < CHUNK) {
    sv = H[0]*xr[tid] + H[1]*xr[CHUNK+tid] + H[2]*xr[2*CHUNK+tid] + H[3]*xr[3*CHUNK+tid];
    s[tid] = sv;
  }
  float sum = sv, sq = sv * sv;
  #pragma unroll
  for (int m = 32; m > 0; m >>= 1) {
    sum += __shfl_down(sum, m);
    sq  += __shfl_down(sq, m);
  }
  if ((tid & 63) == 0) { part[tid >> 6] = sum; part[4 + (tid >> 6)] = sq; }
  __syncthreads();
  if (tid == 0) {
    float S = part[0] + part[1] + part[2] + part[3];
    float Q = part[4] + part[5] + part[6] + part[7];
    float mu = S * (1.f / CHUNK);
    float var = Q * (1.f / CHUNK) - mu * mu;
    red[0] = mu;
    red[1] = rsqrtf(var + 1e-5f);
  }
  __syncthreads();
  const float mu = red[0], rs = red[1];
  bf16* orow = out + (size_t)t * EMBED;
  #pragma unroll
  for (int r = 0; r < 3; ++r) {
    const int d = tid + r * 256;
    const float v = (s[d % CHUNK] - mu) * rs * g[d] + b[d];
    orow[d] = (bf16)v;
  }
}

// ----------------------------------------------------------------- gemm ----
// C[m,n] = sum_k A[m,k]*B[n,k] + bias[n]; bf16 row-major A (MxK), B (NxK).
// 128x128 tile, BK=32, 32x32x16 MFMA, 3-buffer LDS pipeline (2-deep
// prefetch, vmcnt(8) steady state). No setprio (lockstep block, m190).
// T1 XCD block swizzle. KSPLIT=2: blockIdx.z halves K; z=1 -> C1, no bias.
// All outputs bf16. LDS swizzle: granule ^= (row>>1)&3; staging
// pre-swizzles the global source, LDS dest linear (rule #21).
template <int GELU, int KSPLIT>
__global__ __launch_bounds__(256, 2) void gemm_bt(
    const bf16* __restrict__ A, const bf16* __restrict__ B,
    const float* __restrict__ bias, bf16* __restrict__ C0,
    bf16* __restrict__ C1, int M, int N, int K) {
  constexpr int BM = 128, BN = 128, BK = 32;
  __shared__ bf16 sA[3][BM * BK];
  __shared__ bf16 sB[3][BN * BK];
  const int tid  = threadIdx.x;
  const int lane = tid & 63;
  const int nwg = gridDim.x * gridDim.y;
  int Lw = blockIdx.y * gridDim.x + blockIdx.x;
  Lw = (Lw & 7) * (nwg >> 3) + (Lw >> 3);
  const int bm = (Lw / gridDim.x) * BM;
  const int bn = (Lw % gridDim.x) * BN;
  const int wave = tid >> 6;
  const int wr = (wave >> 1) * 64;
  const int wc = (wave & 1) * 64;
  f32x16 acc[2][2] = {};
  const int tr = tid >> 2;
  const int gt = tid & 3;
  const int gsw = (gt ^ ((tr >> 1) & 3)) * 8;   // inverse-swizzled source granule
  const int kbeg = (KSPLIT > 1) ? blockIdx.z * (K / KSPLIT) : 0;
  const bf16* Ag = A + (size_t)(bm + tr) * K + kbeg + gsw;
  const bf16* Bg = B + (size_t)(bn + tr) * K + kbeg + gsw;
  const int lofs = tr * BK + gt * 8;
  const int r31 = lane & 31, rh = lane >> 5;
  const int asw = (r31 >> 1) & 3;               // read-side swizzle (row bits 2:1)
  const int nst = K / KSPLIT / BK;
#define STAGE(buf, t)                                                         \
  do { const int bk_ = (t) * BK;                                              \
    GLDS16(Ag + bk_, sA[buf] + lofs);                                         \
    GLDS16(Ag + (size_t)64 * K + bk_, sA[buf] + lofs + 64 * BK);              \
    GLDS16(Bg + bk_, sB[buf] + lofs);                                         \
    GLDS16(Bg + (size_t)64 * K + bk_, sB[buf] + lofs + 64 * BK);              \
  } while (0)
  STAGE(0, 0);
  STAGE(1, 1);
  int cur = 0;
  for (int t = 0; t < nst; ++t) {
    if (t + 2 < nst) {
      const int nb = cur + 2 >= 3 ? cur - 1 : cur + 2;
      STAGE(nb, t + 2);
      asm volatile("s_waitcnt vmcnt(8)" ::: "memory");
    } else if (t + 1 < nst) {
      asm volatile("s_waitcnt vmcnt(4)" ::: "memory");
    } else {
      asm volatile("s_waitcnt vmcnt(0)" ::: "memory");
    }
    BARRIER();
    bf16x8 af[2][2], bfr[2][2];
    #pragma unroll
    for (int ks = 0; ks < 2; ++ks) {
      const int pos = ((ks * 2 + rh) ^ asw) * 8;
      #pragma unroll
      for (int i = 0; i < 2; ++i) {
        af[i][ks]  = *(const bf16x8*)(sA[cur] + (wr + i * 32 + r31) * BK + pos);
        bfr[i][ks] = *(const bf16x8*)(sB[cur] + (wc + i * 32 + r31) * BK + pos);
      }
    }
    #pragma unroll
    for (int ks = 0; ks < 2; ++ks)
      #pragma unroll
      for (int i = 0; i < 2; ++i)
        #pragma unroll
        for (int j = 0; j < 2; ++j)
          acc[i][j] = __builtin_amdgcn_mfma_f32_32x32x16_bf16(af[i][ks], bfr[j][ks], acc[i][j], 0, 0, 0);
    BARRIER();
    cur = cur == 2 ? 0 : cur + 1;
  }
#undef STAGE
  // C/D 32x32 layout: col = lane&31, row = (reg&3) + 8*(reg>>2) + 4*(lane>>5)
  const bool second = (KSPLIT > 1) && (blockIdx.z != 0);
  bf16* Co = second ? C1 : C0;
  #pragma unroll
  for (int j = 0; j < 2; ++j) {
    const int col = bn + wc + j * 32 + r31;
    const float bv = second ? 0.f : bias[col];
    #pragma unroll
    for (int i = 0; i < 2; ++i) {
      const int row0 = bm + wr + i * 32 + 4 * rh;
      #pragma unroll
      for (int reg = 0; reg < 16; ++reg) {
        const int row = row0 + (reg & 3) + 8 * (reg >> 2);
        float v = acc[i][j][reg] + bv;
        if (GELU) {
          // tanh-approx GELU via hw exp (clamped against overflow)
          float u = 0.7978845608f * (v + 0.044715f * v * v * v);
          u = fmaxf(fminf(u, 15.f), -15.f);
          const float e = __expf(-2.f * u);
          v = v / (1.f + e);             // 0.5*v*(1+tanh(u)) == v/(1+e^{-2u})
        }
        Co[(size_t)row * N + col] = (bf16)v;
      }
    }
  }
}

// ------------------------------------------------------------------- vt ----
// VT[bh][hd][tok] = qkv[bb*1024+tok][1536 + h*64 + hd]; swizzled LDS stage.
__global__ __launch_bounds__(256) void vt_kernel(const bf16* __restrict__ qkv,
                                                 bf16* __restrict__ VT) {
  const int tt = blockIdx.x;   // 16 tok tiles of 64
  const int bh = blockIdx.y;   // 96
  const int bb = bh / HEADS;
  const int h = bh - bb * HEADS;
  __shared__ bf16 sT[64 * 64];
  const int t = threadIdx.x;
  const int srow = t >> 3;            // 0..31 (tok within half-tile)
  const int g = t & 7;                // 16B granule
  const int gs = ((g ^ (srow & 7)) * 8);
  const bf16* Vg = qkv + ((size_t)(bb * SEQ + tt * 64 + srow)) * 2304 + 1536 + h * 64;
  GLDS16(Vg + gs, sT + srow * 64 + g * 8);
  GLDS16(Vg + (size_t)32 * 2304 + gs, sT + (32 + srow) * 64 + g * 8);
  __syncthreads();
  const int hd = t >> 2;
  const int tg = (t & 3) * 16;
  bf16 tmp[16];
  #pragma unroll
  for (int j = 0; j < 16; ++j) {
    const int tok = tg + j;
    tmp[j] = sT[tok * 64 + (hd ^ ((tok & 7) << 3))];
  }
  bf16* op = VT + (size_t)bh * (HD * SEQ) + (size_t)hd * SEQ + tt * 64 + tg;
  *(bf16x8*)(op) = *(const bf16x8*)(tmp);
  *(bf16x8*)(op + 8) = *(const bf16x8*)(tmp + 8);
}

// ----------------------------------------------------------------- attn ----
// Flash attention with FIXED-MAX softmax (M = 0): softmax is shift-
// invariant, and for this op scores = (LN q)·(LN k)/8 are bounded (row
// norms ~5 ⇒ |s/8| ≤ ~5, f32 exp overflows at 88 — margin ~17×), so the
// online max tree / rescale are unnecessary: p = exp(s/8), l via ones-row
// MFMA, final O /= l. Removes 16 shfl + 28 fmax + rescale per k-tile.
// Swizzled LDS, double-buffered K/V, XCD-chunked mapping, setprio (m191).
__global__ __launch_bounds__(256) void attn_kernel(
    const bf16* __restrict__ qkv, const bf16* __restrict__ VT,
    bf16* __restrict__ out) {
  const int lin = blockIdx.x;
  const int qt = (lin >> 3) & 15;
  const int bh = (lin & 7) + 8 * (lin >> 7);
  const int bb = bh / HEADS;
  const int h = bh - bb * HEADS;
  const int tid = threadIdx.x;
  const int lane = tid & 63;
  const int wave = tid >> 6;
  const size_t tokBase = (size_t)bb * SEQ;
  const int q0 = qt * 64;

  __shared__ bf16 sQ[64 * 64];
  __shared__ bf16 sK[2][64 * 64];
  __shared__ bf16 sV[2][80 * 64];   // rows 0..63 V^T tile; row 64 = ones, 65..79 = 0
  __shared__ bf16 sP[4][16 * 64];   // per wave, swizzled

  for (int idx = tid; idx < 16 * 64; idx += 256) {
    const bf16 v = (idx < 64) ? (bf16)1.f : (bf16)0.f;
    sV[0][64 * 64 + idx] = v;
    sV[1][64 * 64 + idx] = v;
  }

  const int srow = tid >> 3;          // 0..31
  const int g = tid & 7;
  const int gs = ((g ^ (srow & 7)) * 8);   // pre-swizzled source granule
  {
    const bf16* Qg = qkv + (tokBase + q0 + srow) * 2304 + h * 64;
    GLDS16(Qg + gs, sQ + srow * 64 + g * 8);
    GLDS16(Qg + (size_t)32 * 2304 + gs, sQ + (32 + srow) * 64 + g * 8);
  }
  __syncthreads();   // drains Q loads, publishes ones rows
  const int l15 = lane & 15, hi = lane >> 4;
  const int ksw = (l15 & 7) << 3;
  bf16x8 qf[2];
  {
    const int qrow = wave * 16 + l15;
    const int qsw = (qrow & 7) << 3;
    #pragma unroll
    for (int ks = 0; ks < 2; ++ks)
      qf[ks] = *(const bf16x8*)(sQ + qrow * 64 + ((hi * 8 + ks * 32) ^ qsw));
  }

  f32x4 o[5] = {};

  const bf16* Kbase = qkv + tokBase * 2304 + 768 + h * 64;
  const bf16* Vbase = VT + (size_t)bh * (HD * SEQ);

  {
    const bf16* Kg = Kbase + (size_t)srow * 2304;
    GLDS16(Kg + gs, sK[0] + srow * 64 + g * 8);
    GLDS16(Kg + (size_t)32 * 2304 + gs, sK[0] + (32 + srow) * 64 + g * 8);
    const bf16* Vg = Vbase + (size_t)srow * SEQ;
    GLDS16(Vg + gs, sV[0] + srow * 64 + g * 8);
    GLDS16(Vg + (size_t)32 * SEQ + gs, sV[0] + (32 + srow) * 64 + g * 8);
  }

  for (int it = 0; it < SEQ / 64; ++it) {
    const int cur = it & 1;
    if (it + 1 < SEQ / 64) {
      const int kb = (it + 1) * 64;
      const bf16* Kg = Kbase + (size_t)(kb + srow) * 2304;
      GLDS16(Kg + gs, sK[cur ^ 1] + srow * 64 + g * 8);
      GLDS16(Kg + (size_t)32 * 2304 + gs, sK[cur ^ 1] + (32 + srow) * 64 + g * 8);
      const bf16* Vg = Vbase + (size_t)srow * SEQ + kb;
      GLDS16(Vg + gs, sV[cur ^ 1] + srow * 64 + g * 8);
      GLDS16(Vg + (size_t)32 * SEQ + gs, sV[cur ^ 1] + (32 + srow) * 64 + g * 8);
      asm volatile("s_waitcnt vmcnt(4)" ::: "memory");
    } else {
      asm volatile("s_waitcnt vmcnt(0)" ::: "memory");
    }
    BARRIER();
    // S = Q K^T  (16 x 64 per wave)
    f32x4 s[4];
    __builtin_amdgcn_s_setprio(1);
    #pragma unroll
    for (int nj = 0; nj < 4; ++nj) {
      s[nj] = (f32x4){0.f, 0.f, 0.f, 0.f};
      #pragma unroll
      for (int ks = 0; ks < 2; ++ks) {
        bf16x8 kf = *(const bf16x8*)(sK[cur] + (nj * 16 + l15) * 64 + ((hi * 8 + ks * 32) ^ ksw));
        s[nj] = __builtin_amdgcn_mfma_f32_16x16x32_bf16(qf[ks], kf, s[nj], 0, 0, 0);
      }
    }
    __builtin_amdgcn_s_setprio(0);
    // fixed-max softmax numerator: p = exp(s/8); P -> LDS (swizzled)
    bf16* Pw = sP[wave];
    #pragma unroll
    for (int r = 0; r < 4; ++r) {
      const int prow = hi * 4 + r;
      const int psw = (prow & 7) << 3;
      #pragma unroll
      for (int nj = 0; nj < 4; ++nj)
        Pw[prow * 64 + ((nj * 16 + l15) ^ psw)] = (bf16)__expf(s[nj][r] * 0.125f);
    }
    // O += P V  (nj = 4 accumulates the row-sum l via the ones row)
    __builtin_amdgcn_s_setprio(1);
    #pragma unroll
    for (int ks = 0; ks < 2; ++ks) {
      bf16x8 pa = *(const bf16x8*)(Pw + l15 * 64 + ((hi * 8 + ks * 32) ^ ksw));
      #pragma unroll
      for (int nj = 0; nj < 5; ++nj) {
        bf16x8 vb = *(const bf16x8*)(sV[cur] + (nj * 16 + l15) * 64 + ((hi * 8 + ks * 32) ^ ksw));
        o[nj] = __builtin_amdgcn_mfma_f32_16x16x32_bf16(pa, vb, o[nj], 0, 0, 0);
      }
    }
    __builtin_amdgcn_s_setprio(0);
    BARRIER();
  }
  #pragma unroll
  for (int r = 0; r < 4; ++r) {
    const float lsum = __shfl(o[4][r], hi << 4, 64);   // lane (hi,l15=0) holds l
    const float inv = 1.f / lsum;
    const size_t row = tokBase + q0 + wave * 16 + hi * 4 + r;
    bf16* orow = out + row * EMBED + h * 64;
    #pragma unroll
    for (int nj = 0; nj < 4; ++nj)
      orow[nj * 16 + l15] = (bf16)(o[nj][r] * inv);
  }
}

// -------------------------------------------------------- combine+preln ----
// Fused block-1 exit / block-2 entry. TWO=1: transform = t + t2 (split-K).
template <int TWO>
__global__ __launch_bounds__(256) void combine_preln_kernel(
    const float* __restrict__ x, const bf16* __restrict__ t,
    const bf16* __restrict__ t2,
    const float* __restrict__ Hres, const float* __restrict__ Hpost,
    const float* __restrict__ Hpre2,
    const float* __restrict__ g2, const float* __restrict__ b2,
    float* __restrict__ X2, bf16* __restrict__ LN) {
  const int tok = blockIdx.x;
  const int tid = threadIdx.x;
  __shared__ float s[CHUNK];
  __shared__ float part[8];
  __shared__ float red[2];
  float sv = 0.f;
  if (tid < CHUNK) {
    const float* xr = x + (size_t)tok * EMBED + tid;
    const bf16* tr = t + (size_t)tok * EMBED + tid;
    const float x0 = xr[0], x1 = xr[CHUNK], x2v = xr[2 * CHUNK], x3 = xr[3 * CHUNK];
    float tm = (float)tr[0] + (float)tr[CHUNK] + (float)tr[2 * CHUNK] + (float)tr[3 * CHUNK];
    if (TWO) {
      const bf16* t2r = t2 + (size_t)tok * EMBED + tid;
      tm += (float)t2r[0] + (float)t2r[CHUNK] + (float)t2r[2 * CHUNK] + (float)t2r[3 * CHUNK];
    }
    tm *= 0.25f;
    float* orow = X2 + (size_t)tok * EMBED + tid;
    #pragma unroll
    for (int n = 0; n < 4; ++n) {
      const float v = Hres[4*n+0]*x0 + Hres[4*n+1]*x1 + Hres[4*n+2]*x2v + Hres[4*n+3]*x3
                    + Hpost[n] * tm;
      orow[n * CHUNK] = v;
      sv += Hpre2[n] * v;
    }
    s[tid] = sv;
  }
  float sum = sv, sq = sv * sv;
  #pragma unroll
  for (int m = 32; m > 0; m >>= 1) {
    sum += __shfl_down(sum, m);
    sq  += __shfl_down(sq, m);
  }
  if ((tid & 63) == 0) { part[tid >> 6] = sum; part[4 + (tid >> 6)] = sq; }
  __syncthreads();
  if (tid == 0) {
    float S = part[0] + part[1] + part[2] + part[3];
    float Q = part[4] + part[5] + part[6] + part[7];
    float mu = S * (1.f / CHUNK);
    float var = Q * (1.f / CHUNK) - mu * mu;
    red[0] = mu;
    red[1] = rsqrtf(var + 1e-5f);
  }
  __syncthreads();
  const float mu = red[0], rs = red[1];
  bf16* lrow = LN + (size_t)tok * EMBED;
  #pragma unroll
  for (int r = 0; r < 3; ++r) {
    const int d = tid + r * 256;
    lrow[d] = (bf16)((s[d % CHUNK] - mu) * rs * g2[d] + b2[d]);
  }
}

// -------------------------------------------------------------- combine ----
// Final combine (writes f32 d_out). TWO=1: transform = t + t2 (split-K).
template <int TWO>
__global__ void combine_kernel(const float* __restrict__ xs, const bf16* __restrict__ t,
                               const bf16* __restrict__ t2,
                               const float* __restrict__ Hres, const float* __restrict__ Hpost,
                               float* __restrict__ outp) {
  const int idx = blockIdx.x * 256 + threadIdx.x;
  if (idx >= TOKENS * CHUNK) return;
  const int tok = idx / CHUNK;
  const int c = idx - tok * CHUNK;
  const float* xr = xs + (size_t)tok * EMBED + c;
  const bf16* tr = t + (size_t)tok * EMBED + c;
  const float x0 = xr[0], x1 = xr[CHUNK], x2 = xr[2 * CHUNK], x3 = xr[3 * CHUNK];
  float tm = (float)tr[0] + (float)tr[CHUNK] + (float)tr[2 * CHUNK] + (float)tr[3 * CHUNK];
  if (TWO) {
    const bf16* t2r = t2 + (size_t)tok * EMBED + c;
    tm += (float)t2r[0] + (float)t2r[CHUNK] + (float)t2r[2 * CHUNK] + (float)t2r[3 * CHUNK];
  }
  tm *= 0.25f;
  #pragma unroll
  for (int n = 0; n < 4; ++n) {
    const float v = Hres[4*n+0]*x0 + Hres[4*n+1]*x1 + Hres[4*n+2]*x2 + Hres[4*n+3]*x3
                  + Hpost[n] * tm;
    outp[(size_t)tok * EMBED + n * CHUNK + c] = v;
  }
}

// ---------------------------------------------------------------- launch ---
extern "C" void kernel_launch(void* const* d_in, const int* in_sizes, int n_in,
                              void* d_out, int out_size, void* d_ws, size_t ws_size,
                              hipStream_t stream) {
  const float* x       = (const float*)d_in[0];
  const float* ln1_g   = (const float*)d_in[1];
  const float* ln1_b   = (const float*)d_in[2];
  const float* ln2_g   = (const float*)d_in[3];
  const float* ln2_b   = (const float*)d_in[4];
  const float* qkv_w   = (const float*)d_in[5];
  const float* qkv_b   = (const float*)d_in[6];
  const float* proj_w  = (const float*)d_in[7];
  const float* proj_b  = (const float*)d_in[8];
  const float* fc1_w   = (const float*)d_in[9];
  const float* fc1_b   = (const float*)d_in[10];
  const float* fc2_w   = (const float*)d_in[11];
  const float* fc2_b   = (const float*)d_in[12];
  const float* a_hres  = (const float*)d_in[13];
  const float* a_hpre  = (const float*)d_in[14];
  const float* a_hpost = (const float*)d_in[15];
  const float* m_hres  = (const float*)d_in[16];
  const float* m_hpre  = (const float*)d_in[17];
  const float* m_hpost = (const float*)d_in[18];

  char* ws = (char*)d_ws;
  float* HS = (float*)(ws);                                  // 48 floats
  bf16* Wq  = (bf16*)(ws + 1024);                            // 2304x768
  bf16* Wp  = (bf16*)(ws + 1024 + 3538944);                  // 768x768
  bf16* W1  = (bf16*)(ws + 1024 + 3538944 + 1179648);        // 3072x768
  bf16* W2  = (bf16*)(ws + 1024 + 3538944 + 1179648 + 4718592); // 768x3072
  bf16* LN  = (bf16*)(ws + 14156800);                        // 8192x768 bf16
  bf16* T   = (bf16*)(ws + 26739712);                        // 8192x768 bf16
  bf16* PT  = (bf16*)(ws + 39322624);                        // 8192x768 bf16 (split-K partial)
  float* X2 = (float*)(ws + 51905536);                       // 8192x768 f32
  bf16* QKV = (bf16*)(ws + 77071360);                        // 8192x2304 bf16
  bf16* AO  = (bf16*)(ws + 114820096);                       // 8192x768 bf16
  bf16* Hm  = (bf16*)(ws + 77071360);                        // 8192x3072 (overlays QKV+AO)
  bf16* VT  = LN;   // 96x64x1024 bf16 — overlays LN (dead after qkv GEMM)

  hprep_kernel<<<1, 64, 0, stream>>>(a_hres, a_hpre, a_hpost, m_hres, m_hpre, m_hpost, HS);
  cvt_kernel<<<1024, 256, 0, stream>>>(qkv_w, Wq, 2304 * 768 / 4);
  cvt_kernel<<<1024, 256, 0, stream>>>(proj_w, Wp, 768 * 768 / 4);
  cvt_kernel<<<1024, 256, 0, stream>>>(fc1_w, W1, 3072 * 768 / 4);
  cvt_kernel<<<1024, 256, 0, stream>>>(fc2_w, W2, 768 * 3072 / 4);

  // ---- block 1: attention mhc ----
  preln_kernel<<<TOKENS, 256, 0, stream>>>(x, HS + 16, ln1_g, ln1_b, LN);
  gemm_bt<0, 1><<<dim3(2304 / 128, TOKENS / 128), 256, 0, stream>>>(
      LN, Wq, qkv_b, QKV, nullptr, TOKENS, 2304, 768);
  vt_kernel<<<dim3(16, 96), 256, 0, stream>>>(QKV, VT);
  attn_kernel<<<1536, 256, 0, stream>>>(QKV, VT, AO);
  // proj with split-K=2 (K=768 -> 2x384): 768 blocks, 3/CU
  gemm_bt<0, 2><<<dim3(768 / 128, TOKENS / 128, 2), 256, 0, stream>>>(
      AO, Wp, proj_b, T, PT, TOKENS, 768, 768);
  // fused: combine block-1 (T+PT) + preLN block-2 (writes X2 f32 + LN bf16)
  combine_preln_kernel<1><<<TOKENS, 256, 0, stream>>>(
      x, T, PT, HS + 0, HS + 20, HS + 24 + 16, ln2_g, ln2_b, X2, LN);

  // ---- block 2: MLP mhc ----
  gemm_bt<1, 1><<<dim3(3072 / 128, TOKENS / 128), 256, 0, stream>>>(
      LN, W1, fc1_b, Hm, nullptr, TOKENS, 3072, 768);
  gemm_bt<0, 2><<<dim3(768 / 128, TOKENS / 128, 2), 256, 0, stream>>>(
      Hm, W2, fc2_b, T, PT, TOKENS, 768, 3072);
  combine_kernel<1><<<(TOKENS * CHUNK + 255) / 256, 256, 0, stream>>>(
      X2, T, PT, HS + 24, HS + 24 + 20, (float*)d_out);
}

// Round 12
// 317.043 us; speedup vs baseline: 1.2866x; 1.0190x over previous
//
#include <hip/hip_runtime.h>
#include <hip/hip_bf16.h>
#include <cstdint>
#include <cstddef>

#define EMBED 768
#define STREAMS 4
#define CHUNK 192          // EMBED / STREAMS
#define HEADS 12
#define HD 64
#define SEQ 1024
#define BATCH 8
#define TOKENS (BATCH * SEQ)   // 8192
#define MLPH 3072

typedef __bf16 bf16;
typedef __bf16 bf16x4 __attribute__((ext_vector_type(4)));
typedef __bf16 bf16x8 __attribute__((ext_vector_type(8)));
typedef float f32x4 __attribute__((ext_vector_type(4)));
typedef float f32x16 __attribute__((ext_vector_type(16)));

// async global->LDS, 16B per lane; LDS dest must be linear in lane order
#define GLDS16(gp, lp)                                                        \
  __builtin_amdgcn_global_load_lds(                                           \
      (const __attribute__((address_space(1))) void*)(gp),                    \
      (__attribute__((address_space(3))) void*)(lp), 16, 0, 0)

// raw barrier (no vmcnt(0) drain) with compiler memory fences on both sides
#define BARRIER() do { asm volatile("" ::: "memory");                         \
  __builtin_amdgcn_s_barrier(); asm volatile("" ::: "memory"); } while (0)

// ----------------------------------------------------------- cvt + hprep ----
// Blocks 0..2047: f32->bf16 weight conversion (4 segments, float4-wide).
// Block 2048 thread 0: Sinkhorn(4x4,20) + softmax(4) for both mhc blocks.
// HS layout: [s*24+0..15] H_res, [16..19] H_pre, [20..23] H_post.
#define CVT_NQ 442368      // 2304*768/4
#define CVT_NP 147456      // 768*768/4
#define CVT_N1 589824      // 3072*768/4
#define CVT_TOT (CVT_NQ + CVT_NP + 2 * CVT_N1)   // 1769472
__global__ __launch_bounds__(256) void cvt_hprep_kernel(
    const float* __restrict__ qw, const float* __restrict__ pw,
    const float* __restrict__ f1w, const float* __restrict__ f2w,
    bf16* __restrict__ Wq, bf16* __restrict__ Wp,
    bf16* __restrict__ W1, bf16* __restrict__ W2,
    const float* ar, const float* ap, const float* ao,
    const float* mr, const float* mp, const float* mo, float* HS) {
  if (blockIdx.x == 2048) {
    if (threadIdx.x != 0) return;
    const float* L[2] = {ar, mr};
    const float* P[2] = {ap, mp};
    const float* O[2] = {ao, mo};
    for (int s = 0; s < 2; ++s) {
      float A[16];
      for (int i = 0; i < 16; ++i) A[i] = expf(L[s][i]);
      for (int it = 0; it < 20; ++it) {
        for (int r = 0; r < 4; ++r) {
          float rs = A[4*r] + A[4*r+1] + A[4*r+2] + A[4*r+3] + 1e-8f;
          for (int c = 0; c < 4; ++c) A[4*r+c] /= rs;
        }
        for (int c = 0; c < 4; ++c) {
          float cs = A[c] + A[4+c] + A[8+c] + A[12+c] + 1e-8f;
          for (int r = 0; r < 4; ++r) A[4*r+c] /= cs;
        }
      }
      float* dst = HS + s * 24;
      for (int i = 0; i < 16; ++i) dst[i] = A[i];
      {
        float m = fmaxf(fmaxf(P[s][0], P[s][1]), fmaxf(P[s][2], P[s][3]));
        float e[4], t = 0.f;
        for (int i = 0; i < 4; ++i) { e[i] = expf(P[s][i] - m); t += e[i]; }
        for (int i = 0; i < 4; ++i) dst[16 + i] = e[i] / t;
      }
      {
        float m = fmaxf(fmaxf(O[s][0], O[s][1]), fmaxf(O[s][2], O[s][3]));
        float e[4], t = 0.f;
        for (int i = 0; i < 4; ++i) { e[i] = expf(O[s][i] - m); t += e[i]; }
        for (int i = 0; i < 4; ++i) dst[20 + i] = e[i] / t;
      }
    }
    return;
  }
  int i = blockIdx.x * 256 + threadIdx.x;
  const int st = 2048 * 256;
  for (; i < CVT_TOT; i += st) {
    const float* src; bf16* dst; int off;
    if (i < CVT_NQ)                      { src = qw;  dst = Wq; off = i; }
    else if (i < CVT_NQ + CVT_NP)        { src = pw;  dst = Wp; off = i - CVT_NQ; }
    else if (i < CVT_NQ + CVT_NP + CVT_N1){ src = f1w; dst = W1; off = i - CVT_NQ - CVT_NP; }
    else                                 { src = f2w; dst = W2; off = i - CVT_NQ - CVT_NP - CVT_N1; }
    const float4 v = ((const float4*)src)[off];
    bf16x4 o = {(bf16)v.x, (bf16)v.y, (bf16)v.z, (bf16)v.w};
    *(bf16x4*)(dst + (size_t)off * 4) = o;
  }
}

// ---------------------------------------------------------------- preln ----
__global__ __launch_bounds__(256) void preln_kernel(
    const float* __restrict__ x, const float* __restrict__ H,
    const float* __restrict__ g, const float* __restrict__ b,
    bf16* __restrict__ out) {
  const int t = blockIdx.x;
  const float* xr = x + (size_t)t * EMBED;
  __shared__ float s[CHUNK];
  __shared__ float part[8];
  __shared__ float red[2];
  const int tid = threadIdx.x;
  float sv = 0.f;
  if (tid < CHUNK) {
    sv = H[0]*xr[tid] + H[1]*xr[CHUNK+tid] + H[2]*xr[2*CHUNK+tid] + H[3]*xr[3*CHUNK+tid];
    s[tid] = sv;
  }
  float sum = sv, sq = sv * sv;
  #pragma unroll
  for (int m = 32; m > 0; m >>= 1) {
    sum += __shfl_down(sum, m);
    sq  += __shfl_down(sq, m);
  }
  if ((tid & 63) == 0) { part[tid >> 6] = sum; part[4 + (tid >> 6)] = sq; }
  __syncthreads();
  if (tid == 0) {
    float S = part[0] + part[1] + part[2] + part[3];
    float Q = part[4] + part[5] + part[6] + part[7];
    float mu = S * (1.f / CHUNK);
    float var = Q * (1.f / CHUNK) - mu * mu;
    red[0] = mu;
    red[1] = rsqrtf(var + 1e-5f);
  }
  __syncthreads();
  const float mu = red[0], rs = red[1];
  bf16* orow = out + (size_t)t * EMBED;
  #pragma unroll
  for (int r = 0; r < 3; ++r) {
    const int d = tid + r * 256;
    const float v = (s[d % CHUNK] - mu) * rs * g[d] + b[d];
    orow[d] = (bf16)v;
  }
}

// ----------------------------------------------------------------- gemm ----
// C[m,n] = sum_k A[m,k]*B[n,k] + bias[n]; bf16 row-major A (MxK), B (NxK).
// 128x128 tile, BK=32, 32x32x16 MFMA, 3-buffer LDS pipeline (2-deep
// prefetch, vmcnt(8) steady state) — VERBATIM the R10 core that passed
// timed replays. No setprio (lockstep block, m190). T1 XCD block swizzle.
// KSPLIT=2: blockIdx.z halves K; z=1 -> C1, no bias. All outputs bf16.
// LDS swizzle: granule ^= (row>>1)&3; staging pre-swizzles global source,
// LDS dest linear (rule #21).
template <int GELU, int KSPLIT>
__global__ __launch_bounds__(256, 2) void gemm_bt(
    const bf16* __restrict__ A, const bf16* __restrict__ B,
    const float* __restrict__ bias, bf16* __restrict__ C0,
    bf16* __restrict__ C1, int M, int N, int K) {
  constexpr int BM = 128, BN = 128, BK = 32;
  __shared__ bf16 sA[3][BM * BK];
  __shared__ bf16 sB[3][BN * BK];
  const int tid  = threadIdx.x;
  const int lane = tid & 63;
  const int nwg = gridDim.x * gridDim.y;
  int Lw = blockIdx.y * gridDim.x + blockIdx.x;
  Lw = (Lw & 7) * (nwg >> 3) + (Lw >> 3);
  const int bm = (Lw / gridDim.x) * BM;
  const int bn = (Lw % gridDim.x) * BN;
  const int wave = tid >> 6;
  const int wr = (wave >> 1) * 64;
  const int wc = (wave & 1) * 64;
  f32x16 acc[2][2] = {};
  const int tr = tid >> 2;
  const int gt = tid & 3;
  const int gsw = (gt ^ ((tr >> 1) & 3)) * 8;   // inverse-swizzled source granule
  const int kbeg = (KSPLIT > 1) ? blockIdx.z * (K / KSPLIT) : 0;
  const bf16* Ag = A + (size_t)(bm + tr) * K + kbeg + gsw;
  const bf16* Bg = B + (size_t)(bn + tr) * K + kbeg + gsw;
  const int lofs = tr * BK + gt * 8;
  const int r31 = lane & 31, rh = lane >> 5;
  const int asw = (r31 >> 1) & 3;               // read-side swizzle (row bits 2:1)
  const int nst = K / KSPLIT / BK;
#define STAGE(buf, t)                                                         \
  do { const int bk_ = (t) * BK;                                              \
    GLDS16(Ag + bk_, sA[buf] + lofs);                                         \
    GLDS16(Ag + (size_t)64 * K + bk_, sA[buf] + lofs + 64 * BK);              \
    GLDS16(Bg + bk_, sB[buf] + lofs);                                         \
    GLDS16(Bg + (size_t)64 * K + bk_, sB[buf] + lofs + 64 * BK);              \
  } while (0)
  STAGE(0, 0);
  STAGE(1, 1);
  int cur = 0;
  for (int t = 0; t < nst; ++t) {
    if (t + 2 < nst) {
      const int nb = cur + 2 >= 3 ? cur - 1 : cur + 2;
      STAGE(nb, t + 2);
      asm volatile("s_waitcnt vmcnt(8)" ::: "memory");
    } else if (t + 1 < nst) {
      asm volatile("s_waitcnt vmcnt(4)" ::: "memory");
    } else {
      asm volatile("s_waitcnt vmcnt(0)" ::: "memory");
    }
    BARRIER();
    bf16x8 af[2][2], bfr[2][2];
    #pragma unroll
    for (int ks = 0; ks < 2; ++ks) {
      const int pos = ((ks * 2 + rh) ^ asw) * 8;
      #pragma unroll
      for (int i = 0; i < 2; ++i) {
        af[i][ks]  = *(const bf16x8*)(sA[cur] + (wr + i * 32 + r31) * BK + pos);
        bfr[i][ks] = *(const bf16x8*)(sB[cur] + (wc + i * 32 + r31) * BK + pos);
      }
    }
    #pragma unroll
    for (int ks = 0; ks < 2; ++ks)
      #pragma unroll
      for (int i = 0; i < 2; ++i)
        #pragma unroll
        for (int j = 0; j < 2; ++j)
          acc[i][j] = __builtin_amdgcn_mfma_f32_32x32x16_bf16(af[i][ks], bfr[j][ks], acc[i][j], 0, 0, 0);
    BARRIER();
    cur = cur == 2 ? 0 : cur + 1;
  }
#undef STAGE
  // C/D 32x32 layout: col = lane&31, row = (reg&3) + 8*(reg>>2) + 4*(lane>>5)
  const bool second = (KSPLIT > 1) && (blockIdx.z != 0);
  bf16* Co = second ? C1 : C0;
  #pragma unroll
  for (int j = 0; j < 2; ++j) {
    const int col = bn + wc + j * 32 + r31;
    const float bv = second ? 0.f : bias[col];
    #pragma unroll
    for (int i = 0; i < 2; ++i) {
      const int row0 = bm + wr + i * 32 + 4 * rh;
      #pragma unroll
      for (int reg = 0; reg < 16; ++reg) {
        const int row = row0 + (reg & 3) + 8 * (reg >> 2);
        float v = acc[i][j][reg] + bv;
        if (GELU) {
          // tanh-approx GELU via hw exp (clamped against overflow)
          float u = 0.7978845608f * (v + 0.044715f * v * v * v);
          u = fmaxf(fminf(u, 15.f), -15.f);
          const float e = __expf(-2.f * u);
          v = v / (1.f + e);             // 0.5*v*(1+tanh(u)) == v/(1+e^{-2u})
        }
        Co[(size_t)row * N + col] = (bf16)v;
      }
    }
  }
}

// ------------------------------------------------------------------- vt ----
// VT[bh][hd][tok] = qkv[bb*1024+tok][1536 + h*64 + hd]; swizzled LDS stage.
__global__ __launch_bounds__(256) void vt_kernel(const bf16* __restrict__ qkv,
                                                 bf16* __restrict__ VT) {
  const int tt = blockIdx.x;   // 16 tok tiles of 64
  const int bh = blockIdx.y;   // 96
  const int bb = bh / HEADS;
  const int h = bh - bb * HEADS;
  __shared__ bf16 sT[64 * 64];
  const int t = threadIdx.x;
  const int srow = t >> 3;            // 0..31 (tok within half-tile)
  const int g = t & 7;                // 16B granule
  const int gs = ((g ^ (srow & 7)) * 8);
  const bf16* Vg = qkv + ((size_t)(bb * SEQ + tt * 64 + srow)) * 2304 + 1536 + h * 64;
  GLDS16(Vg + gs, sT + srow * 64 + g * 8);
  GLDS16(Vg + (size_t)32 * 2304 + gs, sT + (32 + srow) * 64 + g * 8);
  __syncthreads();
  const int hd = t >> 2;
  const int tg = (t & 3) * 16;
  bf16 tmp[16];
  #pragma unroll
  for (int j = 0; j < 16; ++j) {
    const int tok = tg + j;
    tmp[j] = sT[tok * 64 + (hd ^ ((tok & 7) << 3))];
  }
  bf16* op = VT + (size_t)bh * (HD * SEQ) + (size_t)hd * SEQ + tt * 64 + tg;
  *(bf16x8*)(op) = *(const bf16x8*)(tmp);
  *(bf16x8*)(op + 8) = *(const bf16x8*)(tmp + 8);
}

// ----------------------------------------------------------------- attn ----
// Flash attention with FIXED-MAX softmax (M = 0): scores = (LN q)·(LN k)/8
// are bounded (|s/8| ≤ ~5 vs f32 exp overflow at 88), so p = exp(s/8) is
// exact; l via ones-row MFMA; final O /= l. Swizzled LDS, double-buffered
// K/V, XCD-chunked mapping, setprio (m191 regime).
__global__ __launch_bounds__(256) void attn_kernel(
    const bf16* __restrict__ qkv, const bf16* __restrict__ VT,
    bf16* __restrict__ out) {
  const int lin = blockIdx.x;
  const int qt = (lin >> 3) & 15;
  const int bh = (lin & 7) + 8 * (lin >> 7);
  const int bb = bh / HEADS;
  const int h = bh - bb * HEADS;
  const int tid = threadIdx.x;
  const int lane = tid & 63;
  const int wave = tid >> 6;
  const size_t tokBase = (size_t)bb * SEQ;
  const int q0 = qt * 64;

  __shared__ bf16 sQ[64 * 64];
  __shared__ bf16 sK[2][64 * 64];
  __shared__ bf16 sV[2][80 * 64];   // rows 0..63 V^T tile; row 64 = ones, 65..79 = 0
  __shared__ bf16 sP[4][16 * 64];   // per wave, swizzled

  for (int idx = tid; idx < 16 * 64; idx += 256) {
    const bf16 v = (idx < 64) ? (bf16)1.f : (bf16)0.f;
    sV[0][64 * 64 + idx] = v;
    sV[1][64 * 64 + idx] = v;
  }

  const int srow = tid >> 3;          // 0..31
  const int g = tid & 7;
  const int gs = ((g ^ (srow & 7)) * 8);   // pre-swizzled source granule
  {
    const bf16* Qg = qkv + (tokBase + q0 + srow) * 2304 + h * 64;
    GLDS16(Qg + gs, sQ + srow * 64 + g * 8);
    GLDS16(Qg + (size_t)32 * 2304 + gs, sQ + (32 + srow) * 64 + g * 8);
  }
  __syncthreads();   // drains Q loads, publishes ones rows
  const int l15 = lane & 15, hi = lane >> 4;
  const int ksw = (l15 & 7) << 3;
  bf16x8 qf[2];
  {
    const int qrow = wave * 16 + l15;
    const int qsw = (qrow & 7) << 3;
    #pragma unroll
    for (int ks = 0; ks < 2; ++ks)
      qf[ks] = *(const bf16x8*)(sQ + qrow * 64 + ((hi * 8 + ks * 32) ^ qsw));
  }

  f32x4 o[5] = {};

  const bf16* Kbase = qkv + tokBase * 2304 + 768 + h * 64;
  const bf16* Vbase = VT + (size_t)bh * (HD * SEQ);

  {
    const bf16* Kg = Kbase + (size_t)srow * 2304;
    GLDS16(Kg + gs, sK[0] + srow * 64 + g * 8);
    GLDS16(Kg + (size_t)32 * 2304 + gs, sK[0] + (32 + srow) * 64 + g * 8);
    const bf16* Vg = Vbase + (size_t)srow * SEQ;
    GLDS16(Vg + gs, sV[0] + srow * 64 + g * 8);
    GLDS16(Vg + (size_t)32 * SEQ + gs, sV[0] + (32 + srow) * 64 + g * 8);
  }

  for (int it = 0; it < SEQ / 64; ++it) {
    const int cur = it & 1;
    if (it + 1 < SEQ / 64) {
      const int kb = (it + 1) * 64;
      const bf16* Kg = Kbase + (size_t)(kb + srow) * 2304;
      GLDS16(Kg + gs, sK[cur ^ 1] + srow * 64 + g * 8);
      GLDS16(Kg + (size_t)32 * 2304 + gs, sK[cur ^ 1] + (32 + srow) * 64 + g * 8);
      const bf16* Vg = Vbase + (size_t)srow * SEQ + kb;
      GLDS16(Vg + gs, sV[cur ^ 1] + srow * 64 + g * 8);
      GLDS16(Vg + (size_t)32 * SEQ + gs, sV[cur ^ 1] + (32 + srow) * 64 + g * 8);
      asm volatile("s_waitcnt vmcnt(4)" ::: "memory");
    } else {
      asm volatile("s_waitcnt vmcnt(0)" ::: "memory");
    }
    BARRIER();
    // S = Q K^T  (16 x 64 per wave)
    f32x4 s[4];
    __builtin_amdgcn_s_setprio(1);
    #pragma unroll
    for (int nj = 0; nj < 4; ++nj) {
      s[nj] = (f32x4){0.f, 0.f, 0.f, 0.f};
      #pragma unroll
      for (int ks = 0; ks < 2; ++ks) {
        bf16x8 kf = *(const bf16x8*)(sK[cur] + (nj * 16 + l15) * 64 + ((hi * 8 + ks * 32) ^ ksw));
        s[nj] = __builtin_amdgcn_mfma_f32_16x16x32_bf16(qf[ks], kf, s[nj], 0, 0, 0);
      }
    }
    __builtin_amdgcn_s_setprio(0);
    // fixed-max softmax numerator: p = exp(s/8); P -> LDS (swizzled)
    bf16* Pw = sP[wave];
    #pragma unroll
    for (int r = 0; r < 4; ++r) {
      const int prow = hi * 4 + r;
      const int psw = (prow & 7) << 3;
      #pragma unroll
      for (int nj = 0; nj < 4; ++nj)
        Pw[prow * 64 + ((nj * 16 + l15) ^ psw)] = (bf16)__expf(s[nj][r] * 0.125f);
    }
    // O += P V  (nj = 4 accumulates the row-sum l via the ones row)
    __builtin_amdgcn_s_setprio(1);
    #pragma unroll
    for (int ks = 0; ks < 2; ++ks) {
      bf16x8 pa = *(const bf16x8*)(Pw + l15 * 64 + ((hi * 8 + ks * 32) ^ ksw));
      #pragma unroll
      for (int nj = 0; nj < 5; ++nj) {
        bf16x8 vb = *(const bf16x8*)(sV[cur] + (nj * 16 + l15) * 64 + ((hi * 8 + ks * 32) ^ ksw));
        o[nj] = __builtin_amdgcn_mfma_f32_16x16x32_bf16(pa, vb, o[nj], 0, 0, 0);
      }
    }
    __builtin_amdgcn_s_setprio(0);
    BARRIER();
  }
  #pragma unroll
  for (int r = 0; r < 4; ++r) {
    const float lsum = __shfl(o[4][r], hi << 4, 64);   // lane (hi,l15=0) holds l
    const float inv = 1.f / lsum;
    const size_t row = tokBase + q0 + wave * 16 + hi * 4 + r;
    bf16* orow = out + row * EMBED + h * 64;
    #pragma unroll
    for (int nj = 0; nj < 4; ++nj)
      orow[nj * 16 + l15] = (bf16)(o[nj][r] * inv);
  }
}

// -------------------------------------------------------- combine+preln ----
// Fused block-1 exit / block-2 entry. TWO=1: transform = t + t2 (split-K).
template <int TWO>
__global__ __launch_bounds__(256) void combine_preln_kernel(
    const float* __restrict__ x, const bf16* __restrict__ t,
    const bf16* __restrict__ t2,
    const float* __restrict__ Hres, const float* __restrict__ Hpost,
    const float* __restrict__ Hpre2,
    const float* __restrict__ g2, const float* __restrict__ b2,
    float* __restrict__ X2, bf16* __restrict__ LN) {
  const int tok = blockIdx.x;
  const int tid = threadIdx.x;
  __shared__ float s[CHUNK];
  __shared__ float part[8];
  __shared__ float red[2];
  float sv = 0.f;
  if (tid < CHUNK) {
    const float* xr = x + (size_t)tok * EMBED + tid;
    const bf16* tr = t + (size_t)tok * EMBED + tid;
    const float x0 = xr[0], x1 = xr[CHUNK], x2v = xr[2 * CHUNK], x3 = xr[3 * CHUNK];
    float tm = (float)tr[0] + (float)tr[CHUNK] + (float)tr[2 * CHUNK] + (float)tr[3 * CHUNK];
    if (TWO) {
      const bf16* t2r = t2 + (size_t)tok * EMBED + tid;
      tm += (float)t2r[0] + (float)t2r[CHUNK] + (float)t2r[2 * CHUNK] + (float)t2r[3 * CHUNK];
    }
    tm *= 0.25f;
    float* orow = X2 + (size_t)tok * EMBED + tid;
    #pragma unroll
    for (int n = 0; n < 4; ++n) {
      const float v = Hres[4*n+0]*x0 + Hres[4*n+1]*x1 + Hres[4*n+2]*x2v + Hres[4*n+3]*x3
                    + Hpost[n] * tm;
      orow[n * CHUNK] = v;
      sv += Hpre2[n] * v;
    }
    s[tid] = sv;
  }
  float sum = sv, sq = sv * sv;
  #pragma unroll
  for (int m = 32; m > 0; m >>= 1) {
    sum += __shfl_down(sum, m);
    sq  += __shfl_down(sq, m);
  }
  if ((tid & 63) == 0) { part[tid >> 6] = sum; part[4 + (tid >> 6)] = sq; }
  __syncthreads();
  if (tid == 0) {
    float S = part[0] + part[1] + part[2] + part[3];
    float Q = part[4] + part[5] + part[6] + part[7];
    float mu = S * (1.f / CHUNK);
    float var = Q * (1.f / CHUNK) - mu * mu;
    red[0] = mu;
    red[1] = rsqrtf(var + 1e-5f);
  }
  __syncthreads();
  const float mu = red[0], rs = red[1];
  bf16* lrow = LN + (size_t)tok * EMBED;
  #pragma unroll
  for (int r = 0; r < 3; ++r) {
    const int d = tid + r * 256;
    lrow[d] = (bf16)((s[d % CHUNK] - mu) * rs * g2[d] + b2[d]);
  }
}

// -------------------------------------------------------------- combine ----
// Final combine (writes f32 d_out). TWO=1: transform = t + t2 (split-K).
template <int TWO>
__global__ void combine_kernel(const float* __restrict__ xs, const bf16* __restrict__ t,
                               const bf16* __restrict__ t2,
                               const float* __restrict__ Hres, const float* __restrict__ Hpost,
                               float* __restrict__ outp) {
  const int idx = blockIdx.x * 256 + threadIdx.x;
  if (idx >= TOKENS * CHUNK) return;
  const int tok = idx / CHUNK;
  const int c = idx - tok * CHUNK;
  const float* xr = xs + (size_t)tok * EMBED + c;
  const bf16* tr = t + (size_t)tok * EMBED + c;
  const float x0 = xr[0], x1 = xr[CHUNK], x2 = xr[2 * CHUNK], x3 = xr[3 * CHUNK];
  float tm = (float)tr[0] + (float)tr[CHUNK] + (float)tr[2 * CHUNK] + (float)tr[3 * CHUNK];
  if (TWO) {
    const bf16* t2r = t2 + (size_t)tok * EMBED + c;
    tm += (float)t2r[0] + (float)t2r[CHUNK] + (float)t2r[2 * CHUNK] + (float)t2r[3 * CHUNK];
  }
  tm *= 0.25f;
  #pragma unroll
  for (int n = 0; n < 4; ++n) {
    const float v = Hres[4*n+0]*x0 + Hres[4*n+1]*x1 + Hres[4*n+2]*x2 + Hres[4*n+3]*x3
                  + Hpost[n] * tm;
    outp[(size_t)tok * EMBED + n * CHUNK + c] = v;
  }
}

// ---------------------------------------------------------------- launch ---
extern "C" void kernel_launch(void* const* d_in, const int* in_sizes, int n_in,
                              void* d_out, int out_size, void* d_ws, size_t ws_size,
                              hipStream_t stream) {
  const float* x       = (const float*)d_in[0];
  const float* ln1_g   = (const float*)d_in[1];
  const float* ln1_b   = (const float*)d_in[2];
  const float* ln2_g   = (const float*)d_in[3];
  const float* ln2_b   = (const float*)d_in[4];
  const float* qkv_w   = (const float*)d_in[5];
  const float* qkv_b   = (const float*)d_in[6];
  const float* proj_w  = (const float*)d_in[7];
  const float* proj_b  = (const float*)d_in[8];
  const float* fc1_w   = (const float*)d_in[9];
  const float* fc1_b   = (const float*)d_in[10];
  const float* fc2_w   = (const float*)d_in[11];
  const float* fc2_b   = (const float*)d_in[12];
  const float* a_hres  = (const float*)d_in[13];
  const float* a_hpre  = (const float*)d_in[14];
  const float* a_hpost = (const float*)d_in[15];
  const float* m_hres  = (const float*)d_in[16];
  const float* m_hpre  = (const float*)d_in[17];
  const float* m_hpost = (const float*)d_in[18];

  char* ws = (char*)d_ws;
  float* HS = (float*)(ws);                                  // 48 floats
  bf16* Wq  = (bf16*)(ws + 1024);                            // 2304x768
  bf16* Wp  = (bf16*)(ws + 1024 + 3538944);                  // 768x768
  bf16* W1  = (bf16*)(ws + 1024 + 3538944 + 1179648);        // 3072x768
  bf16* W2  = (bf16*)(ws + 1024 + 3538944 + 1179648 + 4718592); // 768x3072
  bf16* LN  = (bf16*)(ws + 14156800);                        // 8192x768 bf16
  bf16* T   = (bf16*)(ws + 26739712);                        // 8192x768 bf16
  bf16* PT  = (bf16*)(ws + 39322624);                        // 8192x768 bf16 (split-K partial)
  float* X2 = (float*)(ws + 51905536);                       // 8192x768 f32
  bf16* QKV = (bf16*)(ws + 77071360);                        // 8192x2304 bf16
  bf16* AO  = (bf16*)(ws + 114820096);                       // 8192x768 bf16
  bf16* Hm  = (bf16*)(ws + 77071360);                        // 8192x3072 (overlays QKV+AO)
  bf16* VT  = LN;   // 96x64x1024 bf16 — overlays LN (dead after qkv GEMM)

  // fused weight-cvt (blocks 0..2047) + Sinkhorn/softmax prep (block 2048)
  cvt_hprep_kernel<<<2049, 256, 0, stream>>>(
      qkv_w, proj_w, fc1_w, fc2_w, Wq, Wp, W1, W2,
      a_hres, a_hpre, a_hpost, m_hres, m_hpre, m_hpost, HS);

  // ---- block 1: attention mhc ----
  preln_kernel<<<TOKENS, 256, 0, stream>>>(x, HS + 16, ln1_g, ln1_b, LN);
  gemm_bt<0, 1><<<dim3(2304 / 128, TOKENS / 128), 256, 0, stream>>>(
      LN, Wq, qkv_b, QKV, nullptr, TOKENS, 2304, 768);
  vt_kernel<<<dim3(16, 96), 256, 0, stream>>>(QKV, VT);
  attn_kernel<<<1536, 256, 0, stream>>>(QKV, VT, AO);
  // proj with split-K=2 (K=768 -> 2x384): 768 blocks
  gemm_bt<0, 2><<<dim3(768 / 128, TOKENS / 128, 2), 256, 0, stream>>>(
      AO, Wp, proj_b, T, PT, TOKENS, 768, 768);
  // fused: combine block-1 (T+PT) + preLN block-2 (writes X2 f32 + LN bf16)
  combine_preln_kernel<1><<<TOKENS, 256, 0, stream>>>(
      x, T, PT, HS + 0, HS + 20, HS + 24 + 16, ln2_g, ln2_b, X2, LN);

  // ---- block 2: MLP mhc ----
  gemm_bt<1, 1><<<dim3(3072 / 128, TOKENS / 128), 256, 0, stream>>>(
      LN, W1, fc1_b, Hm, nullptr, TOKENS, 3072, 768);
  gemm_bt<0, 2><<<dim3(768 / 128, TOKENS / 128, 2), 256, 0, stream>>>(
      Hm, W2, fc2_b, T, PT, TOKENS, 768, 3072);
  combine_kernel<1><<<(TOKENS * CHUNK + 255) / 256, 256, 0, stream>>>(
      X2, T, PT, HS + 24, HS + 24 + 20, (float*)d_out);
}

// Round 13
// 312.881 us; speedup vs baseline: 1.3038x; 1.0133x over previous
//
#include <hip/hip_runtime.h>
#include <hip/hip_bf16.h>
#include <cstdint>
#include <cstddef>

#define EMBED 768
#define STREAMS 4
#define CHUNK 192          // EMBED / STREAMS
#define HEADS 12
#define HD 64
#define SEQ 1024
#define BATCH 8
#define TOKENS (BATCH * SEQ)   // 8192
#define MLPH 3072

typedef __bf16 bf16;
typedef __bf16 bf16x4 __attribute__((ext_vector_type(4)));
typedef __bf16 bf16x8 __attribute__((ext_vector_type(8)));
typedef float f32x4 __attribute__((ext_vector_type(4)));
typedef float f32x16 __attribute__((ext_vector_type(16)));

// async global->LDS, 16B per lane; LDS dest must be linear in lane order
#define GLDS16(gp, lp)                                                        \
  __builtin_amdgcn_global_load_lds(                                           \
      (const __attribute__((address_space(1))) void*)(gp),                    \
      (__attribute__((address_space(3))) void*)(lp), 16, 0, 0)

// raw barrier (no vmcnt(0) drain) with compiler memory fences on both sides
#define BARRIER() do { asm volatile("" ::: "memory");                         \
  __builtin_amdgcn_s_barrier(); asm volatile("" ::: "memory"); } while (0)

// ----------------------------------------------------------- cvt + hprep ----
// Blocks 0..2047: f32->bf16 weight conversion (4 segments, float4-wide).
// Block 2048 thread 0: Sinkhorn(4x4,20) + softmax(4) for both mhc blocks.
// HS layout: [s*24+0..15] H_res, [16..19] H_pre, [20..23] H_post.
#define CVT_NQ 442368      // 2304*768/4
#define CVT_NP 147456      // 768*768/4
#define CVT_N1 589824      // 3072*768/4
#define CVT_TOT (CVT_NQ + CVT_NP + 2 * CVT_N1)   // 1769472
__global__ __launch_bounds__(256) void cvt_hprep_kernel(
    const float* __restrict__ qw, const float* __restrict__ pw,
    const float* __restrict__ f1w, const float* __restrict__ f2w,
    bf16* __restrict__ Wq, bf16* __restrict__ Wp,
    bf16* __restrict__ W1, bf16* __restrict__ W2,
    const float* ar, const float* ap, const float* ao,
    const float* mr, const float* mp, const float* mo, float* HS) {
  if (blockIdx.x == 2048) {
    if (threadIdx.x != 0) return;
    const float* L[2] = {ar, mr};
    const float* P[2] = {ap, mp};
    const float* O[2] = {ao, mo};
    for (int s = 0; s < 2; ++s) {
      float A[16];
      for (int i = 0; i < 16; ++i) A[i] = expf(L[s][i]);
      for (int it = 0; it < 20; ++it) {
        for (int r = 0; r < 4; ++r) {
          float rs = A[4*r] + A[4*r+1] + A[4*r+2] + A[4*r+3] + 1e-8f;
          for (int c = 0; c < 4; ++c) A[4*r+c] /= rs;
        }
        for (int c = 0; c < 4; ++c) {
          float cs = A[c] + A[4+c] + A[8+c] + A[12+c] + 1e-8f;
          for (int r = 0; r < 4; ++r) A[4*r+c] /= cs;
        }
      }
      float* dst = HS + s * 24;
      for (int i = 0; i < 16; ++i) dst[i] = A[i];
      {
        float m = fmaxf(fmaxf(P[s][0], P[s][1]), fmaxf(P[s][2], P[s][3]));
        float e[4], t = 0.f;
        for (int i = 0; i < 4; ++i) { e[i] = expf(P[s][i] - m); t += e[i]; }
        for (int i = 0; i < 4; ++i) dst[16 + i] = e[i] / t;
      }
      {
        float m = fmaxf(fmaxf(O[s][0], O[s][1]), fmaxf(O[s][2], O[s][3]));
        float e[4], t = 0.f;
        for (int i = 0; i < 4; ++i) { e[i] = expf(O[s][i] - m); t += e[i]; }
        for (int i = 0; i < 4; ++i) dst[20 + i] = e[i] / t;
      }
    }
    return;
  }
  int i = blockIdx.x * 256 + threadIdx.x;
  const int st = 2048 * 256;
  for (; i < CVT_TOT; i += st) {
    const float* src; bf16* dst; int off;
    if (i < CVT_NQ)                      { src = qw;  dst = Wq; off = i; }
    else if (i < CVT_NQ + CVT_NP)        { src = pw;  dst = Wp; off = i - CVT_NQ; }
    else if (i < CVT_NQ + CVT_NP + CVT_N1){ src = f1w; dst = W1; off = i - CVT_NQ - CVT_NP; }
    else                                 { src = f2w; dst = W2; off = i - CVT_NQ - CVT_NP - CVT_N1; }
    const float4 v = ((const float4*)src)[off];
    bf16x4 o = {(bf16)v.x, (bf16)v.y, (bf16)v.z, (bf16)v.w};
    *(bf16x4*)(dst + (size_t)off * 4) = o;
  }
}

// ---------------------------------------------------------------- preln ----
__global__ __launch_bounds__(256) void preln_kernel(
    const float* __restrict__ x, const float* __restrict__ H,
    const float* __restrict__ g, const float* __restrict__ b,
    bf16* __restrict__ out) {
  const int t = blockIdx.x;
  const float* xr = x + (size_t)t * EMBED;
  __shared__ float s[CHUNK];
  __shared__ float part[8];
  __shared__ float red[2];
  const int tid = threadIdx.x;
  float sv = 0.f;
  if (tid < CHUNK) {
    sv = H[0]*xr[tid] + H[1]*xr[CHUNK+tid] + H[2]*xr[2*CHUNK+tid] + H[3]*xr[3*CHUNK+tid];
    s[tid] = sv;
  }
  float sum = sv, sq = sv * sv;
  #pragma unroll
  for (int m = 32; m > 0; m >>= 1) {
    sum += __shfl_down(sum, m);
    sq  += __shfl_down(sq, m);
  }
  if ((tid & 63) == 0) { part[tid >> 6] = sum; part[4 + (tid >> 6)] = sq; }
  __syncthreads();
  if (tid == 0) {
    float S = part[0] + part[1] + part[2] + part[3];
    float Q = part[4] + part[5] + part[6] + part[7];
    float mu = S * (1.f / CHUNK);
    float var = Q * (1.f / CHUNK) - mu * mu;
    red[0] = mu;
    red[1] = rsqrtf(var + 1e-5f);
  }
  __syncthreads();
  const float mu = red[0], rs = red[1];
  bf16* orow = out + (size_t)t * EMBED;
  #pragma unroll
  for (int r = 0; r < 3; ++r) {
    const int d = tid + r * 256;
    const float v = (s[d % CHUNK] - mu) * rs * g[d] + b[d];
    orow[d] = (bf16)v;
  }
}

// ----------------------------------------------------------------- gemm ----
// VERBATIM R10/R12 core (passed timed replays). 128x128 tile, BK=32,
// 32x32x16 MFMA, 3-buffer LDS ring (STAGE t+2 -> vmcnt(8) -> barrier).
// No setprio (lockstep block, m190). T1 XCD block swizzle.
// KSPLIT=2: blockIdx.z halves K; z=1 -> C1, no bias. All outputs bf16.
template <int GELU, int KSPLIT>
__global__ __launch_bounds__(256, 2) void gemm_bt(
    const bf16* __restrict__ A, const bf16* __restrict__ B,
    const float* __restrict__ bias, bf16* __restrict__ C0,
    bf16* __restrict__ C1, int M, int N, int K) {
  constexpr int BM = 128, BN = 128, BK = 32;
  __shared__ bf16 sA[3][BM * BK];
  __shared__ bf16 sB[3][BN * BK];
  const int tid  = threadIdx.x;
  const int lane = tid & 63;
  const int nwg = gridDim.x * gridDim.y;
  int Lw = blockIdx.y * gridDim.x + blockIdx.x;
  Lw = (Lw & 7) * (nwg >> 3) + (Lw >> 3);
  const int bm = (Lw / gridDim.x) * BM;
  const int bn = (Lw % gridDim.x) * BN;
  const int wave = tid >> 6;
  const int wr = (wave >> 1) * 64;
  const int wc = (wave & 1) * 64;
  f32x16 acc[2][2] = {};
  const int tr = tid >> 2;
  const int gt = tid & 3;
  const int gsw = (gt ^ ((tr >> 1) & 3)) * 8;   // inverse-swizzled source granule
  const int kbeg = (KSPLIT > 1) ? blockIdx.z * (K / KSPLIT) : 0;
  const bf16* Ag = A + (size_t)(bm + tr) * K + kbeg + gsw;
  const bf16* Bg = B + (size_t)(bn + tr) * K + kbeg + gsw;
  const int lofs = tr * BK + gt * 8;
  const int r31 = lane & 31, rh = lane >> 5;
  const int asw = (r31 >> 1) & 3;               // read-side swizzle (row bits 2:1)
  const int nst = K / KSPLIT / BK;
#define STAGE(buf, t)                                                         \
  do { const int bk_ = (t) * BK;                                              \
    GLDS16(Ag + bk_, sA[buf] + lofs);                                         \
    GLDS16(Ag + (size_t)64 * K + bk_, sA[buf] + lofs + 64 * BK);              \
    GLDS16(Bg + bk_, sB[buf] + lofs);                                         \
    GLDS16(Bg + (size_t)64 * K + bk_, sB[buf] + lofs + 64 * BK);              \
  } while (0)
  STAGE(0, 0);
  STAGE(1, 1);
  int cur = 0;
  for (int t = 0; t < nst; ++t) {
    if (t + 2 < nst) {
      const int nb = cur + 2 >= 3 ? cur - 1 : cur + 2;
      STAGE(nb, t + 2);
      asm volatile("s_waitcnt vmcnt(8)" ::: "memory");
    } else if (t + 1 < nst) {
      asm volatile("s_waitcnt vmcnt(4)" ::: "memory");
    } else {
      asm volatile("s_waitcnt vmcnt(0)" ::: "memory");
    }
    BARRIER();
    bf16x8 af[2][2], bfr[2][2];
    #pragma unroll
    for (int ks = 0; ks < 2; ++ks) {
      const int pos = ((ks * 2 + rh) ^ asw) * 8;
      #pragma unroll
      for (int i = 0; i < 2; ++i) {
        af[i][ks]  = *(const bf16x8*)(sA[cur] + (wr + i * 32 + r31) * BK + pos);
        bfr[i][ks] = *(const bf16x8*)(sB[cur] + (wc + i * 32 + r31) * BK + pos);
      }
    }
    #pragma unroll
    for (int ks = 0; ks < 2; ++ks)
      #pragma unroll
      for (int i = 0; i < 2; ++i)
        #pragma unroll
        for (int j = 0; j < 2; ++j)
          acc[i][j] = __builtin_amdgcn_mfma_f32_32x32x16_bf16(af[i][ks], bfr[j][ks], acc[i][j], 0, 0, 0);
    BARRIER();
    cur = cur == 2 ? 0 : cur + 1;
  }
#undef STAGE
  // C/D 32x32 layout: col = lane&31, row = (reg&3) + 8*(reg>>2) + 4*(lane>>5)
  const bool second = (KSPLIT > 1) && (blockIdx.z != 0);
  bf16* Co = second ? C1 : C0;
  #pragma unroll
  for (int j = 0; j < 2; ++j) {
    const int col = bn + wc + j * 32 + r31;
    const float bv = second ? 0.f : bias[col];
    #pragma unroll
    for (int i = 0; i < 2; ++i) {
      const int row0 = bm + wr + i * 32 + 4 * rh;
      #pragma unroll
      for (int reg = 0; reg < 16; ++reg) {
        const int row = row0 + (reg & 3) + 8 * (reg >> 2);
        float v = acc[i][j][reg] + bv;
        if (GELU) {
          // tanh-approx GELU via hw exp (clamped against overflow)
          float u = 0.7978845608f * (v + 0.044715f * v * v * v);
          u = fmaxf(fminf(u, 15.f), -15.f);
          const float e = __expf(-2.f * u);
          v = v / (1.f + e);             // 0.5*v*(1+tanh(u)) == v/(1+e^{-2u})
        }
        Co[(size_t)row * N + col] = (bf16)v;
      }
    }
  }
}

// ------------------------------------------------------------------- vt ----
// VT[bh][hd][tok] = qkv[bb*1024+tok][1536 + h*64 + hd]; swizzled LDS stage.
__global__ __launch_bounds__(256) void vt_kernel(const bf16* __restrict__ qkv,
                                                 bf16* __restrict__ VT) {
  const int tt = blockIdx.x;   // 16 tok tiles of 64
  const int bh = blockIdx.y;   // 96
  const int bb = bh / HEADS;
  const int h = bh - bb * HEADS;
  __shared__ bf16 sT[64 * 64];
  const int t = threadIdx.x;
  const int srow = t >> 3;            // 0..31 (tok within half-tile)
  const int g = t & 7;                // 16B granule
  const int gs = ((g ^ (srow & 7)) * 8);
  const bf16* Vg = qkv + ((size_t)(bb * SEQ + tt * 64 + srow)) * 2304 + 1536 + h * 64;
  GLDS16(Vg + gs, sT + srow * 64 + g * 8);
  GLDS16(Vg + (size_t)32 * 2304 + gs, sT + (32 + srow) * 64 + g * 8);
  __syncthreads();
  const int hd = t >> 2;
  const int tg = (t & 3) * 16;
  bf16 tmp[16];
  #pragma unroll
  for (int j = 0; j < 16; ++j) {
    const int tok = tg + j;
    tmp[j] = sT[tok * 64 + (hd ^ ((tok & 7) << 3))];
  }
  bf16* op = VT + (size_t)bh * (HD * SEQ) + (size_t)hd * SEQ + tt * 64 + tg;
  *(bf16x8*)(op) = *(const bf16x8*)(tmp);
  *(bf16x8*)(op + 8) = *(const bf16x8*)(tmp + 8);
}

// ----------------------------------------------------------------- attn ----
// Flash attention, QBLK=128 (8 waves / 512 threads, each wave 16 q-rows).
// Fixed-max softmax (scores bounded: |s/8| <= ~5 vs f32 exp overflow 88);
// l via ones-row MFMA; final O /= l. 2-buffer K/V ring with the proven
// STAGE->vmcnt(counted)->barrier skeleton (1 GLDS16/thread per operand per
// tile at 512 thr). Swizzled LDS (granule ^= row&7). XCD-chunked mapping:
// lin = b0 + 8*qt + 64*b1; all 8 q-blocks of one bh land on one XCD.
__global__ __launch_bounds__(512) void attn_kernel(
    const bf16* __restrict__ qkv, const bf16* __restrict__ VT,
    bf16* __restrict__ out) {
  const int lin = blockIdx.x;            // 768 blocks
  const int qt = (lin >> 3) & 7;         // 8 q-tiles of 128
  const int bh = (lin & 7) + 8 * (lin >> 6);
  const int bb = bh / HEADS;
  const int h = bh - bb * HEADS;
  const int tid = threadIdx.x;
  const int lane = tid & 63;
  const int wave = tid >> 6;             // 0..7
  const size_t tokBase = (size_t)bb * SEQ;
  const int q0 = qt * 128;

  __shared__ bf16 sQ[128 * 64];     // 16 KB
  __shared__ bf16 sK[2][64 * 64];   // 16 KB
  __shared__ bf16 sV[2][80 * 64];   // 20 KB; rows 64.. = ones row + zeros
  __shared__ bf16 sP[8][16 * 64];   // 16 KB, per wave, swizzled

  // init ones/zero rows of both V buffers
  for (int idx = tid; idx < 16 * 64; idx += 512) {
    const bf16 v = (idx < 64) ? (bf16)1.f : (bf16)0.f;
    sV[0][64 * 64 + idx] = v;
    sV[1][64 * 64 + idx] = v;
  }

  // Q staging: 128 rows x 8 granules = 1024 slots; 2 per thread
  {
    #pragma unroll
    for (int kq = 0; kq < 2; ++kq) {
      const int slot = tid + kq * 512;
      const int qr = slot >> 3;
      const int qg = slot & 7;
      const bf16* Qg = qkv + (tokBase + q0 + qr) * 2304 + h * 64;
      GLDS16(Qg + ((qg ^ (qr & 7)) * 8), sQ + qr * 64 + qg * 8);
    }
  }
  // K/V staging geometry: 64 rows x 8 granules = 512 slots = 1/thread
  const int srow = tid >> 3;          // 0..63
  const int g = tid & 7;
  const int gs = ((g ^ (srow & 7)) * 8);   // pre-swizzled source granule
  const bf16* Kbase = qkv + tokBase * 2304 + 768 + h * 64;
  const bf16* Vbase = VT + (size_t)bh * (HD * SEQ);
  // prologue: stage tile 0 into buf 0 (1 issue per operand per thread)
  GLDS16(Kbase + (size_t)srow * 2304 + gs, sK[0] + srow * 64 + g * 8);
  GLDS16(Vbase + (size_t)srow * SEQ + gs, sV[0] + srow * 64 + g * 8);
  __syncthreads();   // drains Q + tile0 loads, publishes ones rows

  const int l15 = lane & 15, hi = lane >> 4;
  const int ksw = (l15 & 7) << 3;
  bf16x8 qf[2];
  {
    const int qrow = wave * 16 + l15;
    const int qsw = (qrow & 7) << 3;
    #pragma unroll
    for (int ks = 0; ks < 2; ++ks)
      qf[ks] = *(const bf16x8*)(sQ + qrow * 64 + ((hi * 8 + ks * 32) ^ qsw));
  }

  f32x4 o[5] = {};

  for (int it = 0; it < SEQ / 64; ++it) {
    const int cur = it & 1;
    if (it + 1 < SEQ / 64) {
      const int kb = (it + 1) * 64;
      GLDS16(Kbase + (size_t)(kb + srow) * 2304 + gs, sK[cur ^ 1] + srow * 64 + g * 8);
      GLDS16(Vbase + (size_t)srow * SEQ + kb + gs, sV[cur ^ 1] + srow * 64 + g * 8);
      asm volatile("s_waitcnt vmcnt(2)" ::: "memory");
    } else {
      asm volatile("s_waitcnt vmcnt(0)" ::: "memory");
    }
    BARRIER();
    // S = Q K^T  (16 x 64 per wave)
    f32x4 s[4];
    __builtin_amdgcn_s_setprio(1);
    #pragma unroll
    for (int nj = 0; nj < 4; ++nj) {
      s[nj] = (f32x4){0.f, 0.f, 0.f, 0.f};
      #pragma unroll
      for (int ks = 0; ks < 2; ++ks) {
        bf16x8 kf = *(const bf16x8*)(sK[cur] + (nj * 16 + l15) * 64 + ((hi * 8 + ks * 32) ^ ksw));
        s[nj] = __builtin_amdgcn_mfma_f32_16x16x32_bf16(qf[ks], kf, s[nj], 0, 0, 0);
      }
    }
    __builtin_amdgcn_s_setprio(0);
    // fixed-max softmax numerator: p = exp(s/8); P -> LDS (swizzled)
    bf16* Pw = sP[wave];
    #pragma unroll
    for (int r = 0; r < 4; ++r) {
      const int prow = hi * 4 + r;
      const int psw = (prow & 7) << 3;
      #pragma unroll
      for (int nj = 0; nj < 4; ++nj)
        Pw[prow * 64 + ((nj * 16 + l15) ^ psw)] = (bf16)__expf(s[nj][r] * 0.125f);
    }
    // O += P V  (nj = 4 accumulates the row-sum l via the ones row)
    __builtin_amdgcn_s_setprio(1);
    #pragma unroll
    for (int ks = 0; ks < 2; ++ks) {
      bf16x8 pa = *(const bf16x8*)(Pw + l15 * 64 + ((hi * 8 + ks * 32) ^ ksw));
      #pragma unroll
      for (int nj = 0; nj < 5; ++nj) {
        bf16x8 vb = *(const bf16x8*)(sV[cur] + (nj * 16 + l15) * 64 + ((hi * 8 + ks * 32) ^ ksw));
        o[nj] = __builtin_amdgcn_mfma_f32_16x16x32_bf16(pa, vb, o[nj], 0, 0, 0);
      }
    }
    __builtin_amdgcn_s_setprio(0);
    BARRIER();
  }
  #pragma unroll
  for (int r = 0; r < 4; ++r) {
    const float lsum = __shfl(o[4][r], hi << 4, 64);   // lane (hi,l15=0) holds l
    const float inv = 1.f / lsum;
    const size_t row = tokBase + q0 + wave * 16 + hi * 4 + r;
    bf16* orow = out + row * EMBED + h * 64;
    #pragma unroll
    for (int nj = 0; nj < 4; ++nj)
      orow[nj * 16 + l15] = (bf16)(o[nj][r] * inv);
  }
}

// -------------------------------------------------------- combine+preln ----
// Fused block-1 exit / block-2 entry. TWO=1: transform = t + t2 (split-K).
template <int TWO>
__global__ __launch_bounds__(256) void combine_preln_kernel(
    const float* __restrict__ x, const bf16* __restrict__ t,
    const bf16* __restrict__ t2,
    const float* __restrict__ Hres, const float* __restrict__ Hpost,
    const float* __restrict__ Hpre2,
    const float* __restrict__ g2, const float* __restrict__ b2,
    float* __restrict__ X2, bf16* __restrict__ LN) {
  const int tok = blockIdx.x;
  const int tid = threadIdx.x;
  __shared__ float s[CHUNK];
  __shared__ float part[8];
  __shared__ float red[2];
  float sv = 0.f;
  if (tid < CHUNK) {
    const float* xr = x + (size_t)tok * EMBED + tid;
    const bf16* tr = t + (size_t)tok * EMBED + tid;
    const float x0 = xr[0], x1 = xr[CHUNK], x2v = xr[2 * CHUNK], x3 = xr[3 * CHUNK];
    float tm = (float)tr[0] + (float)tr[CHUNK] + (float)tr[2 * CHUNK] + (float)tr[3 * CHUNK];
    if (TWO) {
      const bf16* t2r = t2 + (size_t)tok * EMBED + tid;
      tm += (float)t2r[0] + (float)t2r[CHUNK] + (float)t2r[2 * CHUNK] + (float)t2r[3 * CHUNK];
    }
    tm *= 0.25f;
    float* orow = X2 + (size_t)tok * EMBED + tid;
    #pragma unroll
    for (int n = 0; n < 4; ++n) {
      const float v = Hres[4*n+0]*x0 + Hres[4*n+1]*x1 + Hres[4*n+2]*x2v + Hres[4*n+3]*x3
                    + Hpost[n] * tm;
      orow[n * CHUNK] = v;
      sv += Hpre2[n] * v;
    }
    s[tid] = sv;
  }
  float sum = sv, sq = sv * sv;
  #pragma unroll
  for (int m = 32; m > 0; m >>= 1) {
    sum += __shfl_down(sum, m);
    sq  += __shfl_down(sq, m);
  }
  if ((tid & 63) == 0) { part[tid >> 6] = sum; part[4 + (tid >> 6)] = sq; }
  __syncthreads();
  if (tid == 0) {
    float S = part[0] + part[1] + part[2] + part[3];
    float Q = part[4] + part[5] + part[6] + part[7];
    float mu = S * (1.f / CHUNK);
    float var = Q * (1.f / CHUNK) - mu * mu;
    red[0] = mu;
    red[1] = rsqrtf(var + 1e-5f);
  }
  __syncthreads();
  const float mu = red[0], rs = red[1];
  bf16* lrow = LN + (size_t)tok * EMBED;
  #pragma unroll
  for (int r = 0; r < 3; ++r) {
    const int d = tid + r * 256;
    lrow[d] = (bf16)((s[d % CHUNK] - mu) * rs * g2[d] + b2[d]);
  }
}

// -------------------------------------------------------------- combine ----
// Final combine (writes f32 d_out). TWO=1: transform = t + t2 (split-K).
template <int TWO>
__global__ void combine_kernel(const float* __restrict__ xs, const bf16* __restrict__ t,
                               const bf16* __restrict__ t2,
                               const float* __restrict__ Hres, const float* __restrict__ Hpost,
                               float* __restrict__ outp) {
  const int idx = blockIdx.x * 256 + threadIdx.x;
  if (idx >= TOKENS * CHUNK) return;
  const int tok = idx / CHUNK;
  const int c = idx - tok * CHUNK;
  const float* xr = xs + (size_t)tok * EMBED + c;
  const bf16* tr = t + (size_t)tok * EMBED + c;
  const float x0 = xr[0], x1 = xr[CHUNK], x2 = xr[2 * CHUNK], x3 = xr[3 * CHUNK];
  float tm = (float)tr[0] + (float)tr[CHUNK] + (float)tr[2 * CHUNK] + (float)tr[3 * CHUNK];
  if (TWO) {
    const bf16* t2r = t2 + (size_t)tok * EMBED + c;
    tm += (float)t2r[0] + (float)t2r[CHUNK] + (float)t2r[2 * CHUNK] + (float)t2r[3 * CHUNK];
  }
  tm *= 0.25f;
  #pragma unroll
  for (int n = 0; n < 4; ++n) {
    const float v = Hres[4*n+0]*x0 + Hres[4*n+1]*x1 + Hres[4*n+2]*x2 + Hres[4*n+3]*x3
                  + Hpost[n] * tm;
    outp[(size_t)tok * EMBED + n * CHUNK + c] = v;
  }
}

// ---------------------------------------------------------------- launch ---
extern "C" void kernel_launch(void* const* d_in, const int* in_sizes, int n_in,
                              void* d_out, int out_size, void* d_ws, size_t ws_size,
                              hipStream_t stream) {
  const float* x       = (const float*)d_in[0];
  const float* ln1_g   = (const float*)d_in[1];
  const float* ln1_b   = (const float*)d_in[2];
  const float* ln2_g   = (const float*)d_in[3];
  const float* ln2_b   = (const float*)d_in[4];
  const float* qkv_w   = (const float*)d_in[5];
  const float* qkv_b   = (const float*)d_in[6];
  const float* proj_w  = (const float*)d_in[7];
  const float* proj_b  = (const float*)d_in[8];
  const float* fc1_w   = (const float*)d_in[9];
  const float* fc1_b   = (const float*)d_in[10];
  const float* fc2_w   = (const float*)d_in[11];
  const float* fc2_b   = (const float*)d_in[12];
  const float* a_hres  = (const float*)d_in[13];
  const float* a_hpre  = (const float*)d_in[14];
  const float* a_hpost = (const float*)d_in[15];
  const float* m_hres  = (const float*)d_in[16];
  const float* m_hpre  = (const float*)d_in[17];
  const float* m_hpost = (const float*)d_in[18];

  char* ws = (char*)d_ws;
  float* HS = (float*)(ws);                                  // 48 floats
  bf16* Wq  = (bf16*)(ws + 1024);                            // 2304x768
  bf16* Wp  = (bf16*)(ws + 1024 + 3538944);                  // 768x768
  bf16* W1  = (bf16*)(ws + 1024 + 3538944 + 1179648);        // 3072x768
  bf16* W2  = (bf16*)(ws + 1024 + 3538944 + 1179648 + 4718592); // 768x3072
  bf16* LN  = (bf16*)(ws + 14156800);                        // 8192x768 bf16
  bf16* T   = (bf16*)(ws + 26739712);                        // 8192x768 bf16
  bf16* PT  = (bf16*)(ws + 39322624);                        // 8192x768 bf16 (split-K partial)
  float* X2 = (float*)(ws + 51905536);                       // 8192x768 f32
  bf16* QKV = (bf16*)(ws + 77071360);                        // 8192x2304 bf16
  bf16* AO  = (bf16*)(ws + 114820096);                       // 8192x768 bf16
  bf16* Hm  = (bf16*)(ws + 77071360);                        // 8192x3072 (overlays QKV+AO)
  bf16* VT  = LN;   // 96x64x1024 bf16 — overlays LN (dead after qkv GEMM)

  // fused weight-cvt (blocks 0..2047) + Sinkhorn/softmax prep (block 2048)
  cvt_hprep_kernel<<<2049, 256, 0, stream>>>(
      qkv_w, proj_w, fc1_w, fc2_w, Wq, Wp, W1, W2,
      a_hres, a_hpre, a_hpost, m_hres, m_hpre, m_hpost, HS);

  // ---- block 1: attention mhc ----
  preln_kernel<<<TOKENS, 256, 0, stream>>>(x, HS + 16, ln1_g, ln1_b, LN);
  gemm_bt<0, 1><<<dim3(2304 / 128, TOKENS / 128), 256, 0, stream>>>(
      LN, Wq, qkv_b, QKV, nullptr, TOKENS, 2304, 768);
  vt_kernel<<<dim3(16, 96), 256, 0, stream>>>(QKV, VT);
  attn_kernel<<<768, 512, 0, stream>>>(QKV, VT, AO);
  // proj with split-K=2 (K=768 -> 2x384): 768 blocks
  gemm_bt<0, 2><<<dim3(768 / 128, TOKENS / 128, 2), 256, 0, stream>>>(
      AO, Wp, proj_b, T, PT, TOKENS, 768, 768);
  // fused: combine block-1 (T+PT) + preLN block-2 (writes X2 f32 + LN bf16)
  combine_preln_kernel<1><<<TOKENS, 256, 0, stream>>>(
      x, T, PT, HS + 0, HS + 20, HS + 24 + 16, ln2_g, ln2_b, X2, LN);

  // ---- block 2: MLP mhc ----
  gemm_bt<1, 1><<<dim3(3072 / 128, TOKENS / 128), 256, 0, stream>>>(
      LN, W1, fc1_b, Hm, nullptr, TOKENS, 3072, 768);
  gemm_bt<0, 2><<<dim3(768 / 128, TOKENS / 128, 2), 256, 0, stream>>>(
      Hm, W2, fc2_b, T, PT, TOKENS, 768, 3072);
  combine_kernel<1><<<(TOKENS * CHUNK + 255) / 256, 256, 0, stream>>>(
      X2, T, PT, HS + 24, HS + 24 + 20, (float*)d_out);
}

// Round 14
// 312.177 us; speedup vs baseline: 1.3067x; 1.0023x over previous
//
#include <hip/hip_runtime.h>
#include <hip/hip_bf16.h>
#include <cstdint>
#include <cstddef>

#define EMBED 768
#define STREAMS 4
#define CHUNK 192          // EMBED / STREAMS
#define HEADS 12
#define HD 64
#define SEQ 1024
#define BATCH 8
#define TOKENS (BATCH * SEQ)   // 8192
#define MLPH 3072

typedef __bf16 bf16;
typedef __bf16 bf16x4 __attribute__((ext_vector_type(4)));
typedef __bf16 bf16x8 __attribute__((ext_vector_type(8)));
typedef float f32x4 __attribute__((ext_vector_type(4)));
typedef float f32x16 __attribute__((ext_vector_type(16)));

// async global->LDS, 16B per lane; LDS dest must be linear in lane order
#define GLDS16(gp, lp)                                                        \
  __builtin_amdgcn_global_load_lds(                                           \
      (const __attribute__((address_space(1))) void*)(gp),                    \
      (__attribute__((address_space(3))) void*)(lp), 16, 0, 0)

// raw barrier (no vmcnt(0) drain) with compiler memory fences on both sides
#define BARRIER() do { asm volatile("" ::: "memory");                         \
  __builtin_amdgcn_s_barrier(); asm volatile("" ::: "memory"); } while (0)

// ------------------------------------------------------------------ head ----
// One launch, three independent jobs:
//   blocks [0, 8192)      : preln for block-1 (computes softmax(a_hpre) locally)
//   blocks [8192, 10240)  : f32->bf16 weight conversion (float4-wide)
//   block 10240, thread 0 : Sinkhorn(4x4,20) + softmax(4) x2 -> HS
// HS layout: [s*24+0..15] H_res, [16..19] H_pre, [20..23] H_post.
#define CVT_NQ 442368      // 2304*768/4
#define CVT_NP 147456      // 768*768/4
#define CVT_N1 589824      // 3072*768/4
#define CVT_TOT (CVT_NQ + CVT_NP + 2 * CVT_N1)   // 1769472
__global__ __launch_bounds__(256) void head_kernel(
    const float* __restrict__ x, const float* __restrict__ ln1_g,
    const float* __restrict__ ln1_b, bf16* __restrict__ LN,
    const float* __restrict__ qw, const float* __restrict__ pw,
    const float* __restrict__ f1w, const float* __restrict__ f2w,
    bf16* __restrict__ Wq, bf16* __restrict__ Wp,
    bf16* __restrict__ W1, bf16* __restrict__ W2,
    const float* ar, const float* ap, const float* ao,
    const float* mr, const float* mp, const float* mo, float* HS) {
  const int tid = threadIdx.x;
  if (blockIdx.x < TOKENS) {
    // ---- preln (block-1), with local softmax(a_hpre) ----
    const int t = blockIdx.x;
    const float* xr = x + (size_t)t * EMBED;
    __shared__ float s[CHUNK];
    __shared__ float part[8];
    __shared__ float red[2];
    float H0, H1, H2, H3;
    {
      const float p0 = ap[0], p1 = ap[1], p2 = ap[2], p3 = ap[3];
      const float m = fmaxf(fmaxf(p0, p1), fmaxf(p2, p3));
      const float e0 = __expf(p0 - m), e1 = __expf(p1 - m),
                  e2 = __expf(p2 - m), e3 = __expf(p3 - m);
      const float inv = 1.f / (e0 + e1 + e2 + e3);
      H0 = e0 * inv; H1 = e1 * inv; H2 = e2 * inv; H3 = e3 * inv;
    }
    float sv = 0.f;
    if (tid < CHUNK) {
      sv = H0*xr[tid] + H1*xr[CHUNK+tid] + H2*xr[2*CHUNK+tid] + H3*xr[3*CHUNK+tid];
      s[tid] = sv;
    }
    float sum = sv, sq = sv * sv;
    #pragma unroll
    for (int m = 32; m > 0; m >>= 1) {
      sum += __shfl_down(sum, m);
      sq  += __shfl_down(sq, m);
    }
    if ((tid & 63) == 0) { part[tid >> 6] = sum; part[4 + (tid >> 6)] = sq; }
    __syncthreads();
    if (tid == 0) {
      float S = part[0] + part[1] + part[2] + part[3];
      float Q = part[4] + part[5] + part[6] + part[7];
      float mu = S * (1.f / CHUNK);
      float var = Q * (1.f / CHUNK) - mu * mu;
      red[0] = mu;
      red[1] = rsqrtf(var + 1e-5f);
    }
    __syncthreads();
    const float mu = red[0], rs = red[1];
    bf16* orow = LN + (size_t)t * EMBED;
    #pragma unroll
    for (int r = 0; r < 3; ++r) {
      const int d = tid + r * 256;
      orow[d] = (bf16)((s[d % CHUNK] - mu) * rs * ln1_g[d] + ln1_b[d]);
    }
    return;
  }
  if (blockIdx.x == TOKENS + 2048) {
    // ---- Sinkhorn + softmaxes -> HS ----
    if (tid != 0) return;
    const float* L[2] = {ar, mr};
    const float* P[2] = {ap, mp};
    const float* O[2] = {ao, mo};
    for (int s = 0; s < 2; ++s) {
      float A[16];
      for (int i = 0; i < 16; ++i) A[i] = expf(L[s][i]);
      for (int it = 0; it < 20; ++it) {
        for (int r = 0; r < 4; ++r) {
          float rs = A[4*r] + A[4*r+1] + A[4*r+2] + A[4*r+3] + 1e-8f;
          for (int c = 0; c < 4; ++c) A[4*r+c] /= rs;
        }
        for (int c = 0; c < 4; ++c) {
          float cs = A[c] + A[4+c] + A[8+c] + A[12+c] + 1e-8f;
          for (int r = 0; r < 4; ++r) A[4*r+c] /= cs;
        }
      }
      float* dst = HS + s * 24;
      for (int i = 0; i < 16; ++i) dst[i] = A[i];
      {
        float m = fmaxf(fmaxf(P[s][0], P[s][1]), fmaxf(P[s][2], P[s][3]));
        float e[4], t = 0.f;
        for (int i = 0; i < 4; ++i) { e[i] = expf(P[s][i] - m); t += e[i]; }
        for (int i = 0; i < 4; ++i) dst[16 + i] = e[i] / t;
      }
      {
        float m = fmaxf(fmaxf(O[s][0], O[s][1]), fmaxf(O[s][2], O[s][3]));
        float e[4], t = 0.f;
        for (int i = 0; i < 4; ++i) { e[i] = expf(O[s][i] - m); t += e[i]; }
        for (int i = 0; i < 4; ++i) dst[20 + i] = e[i] / t;
      }
    }
    return;
  }
  // ---- weight cvt ----
  int i = (blockIdx.x - TOKENS) * 256 + tid;
  const int st = 2048 * 256;
  for (; i < CVT_TOT; i += st) {
    const float* src; bf16* dst; int off;
    if (i < CVT_NQ)                      { src = qw;  dst = Wq; off = i; }
    else if (i < CVT_NQ + CVT_NP)        { src = pw;  dst = Wp; off = i - CVT_NQ; }
    else if (i < CVT_NQ + CVT_NP + CVT_N1){ src = f1w; dst = W1; off = i - CVT_NQ - CVT_NP; }
    else                                 { src = f2w; dst = W2; off = i - CVT_NQ - CVT_NP - CVT_N1; }
    const float4 v = ((const float4*)src)[off];
    bf16x4 o = {(bf16)v.x, (bf16)v.y, (bf16)v.z, (bf16)v.w};
    *(bf16x4*)(dst + (size_t)off * 4) = o;
  }
}

// ----------------------------------------------------------------- gemm ----
// VERBATIM R10/R12 sync core (passed timed replays): 128x128 tile, BK=32,
// 32x32x16 MFMA, 3-buffer LDS ring (STAGE t+2 -> vmcnt(8) -> barrier).
// NEW (index-only): XCD row-band block remap — XCD x owns rows
// [x*gy/8,(x+1)*gy/8), column-major within, so the per-XCD A working set
// (gy/8 row-panels = 1.6 MB) fits its 4 MB L2 and B panels get band reuse.
// KSPLIT=2: blockIdx.z halves K; z=1 -> C1, no bias. All outputs bf16.
template <int GELU, int KSPLIT>
__global__ __launch_bounds__(256, 2) void gemm_bt(
    const bf16* __restrict__ A, const bf16* __restrict__ B,
    const float* __restrict__ bias, bf16* __restrict__ C0,
    bf16* __restrict__ C1, int M, int N, int K) {
  constexpr int BM = 128, BN = 128, BK = 32;
  __shared__ bf16 sA[3][BM * BK];
  __shared__ bf16 sB[3][BN * BK];
  const int tid  = threadIdx.x;
  const int lane = tid & 63;
  // XCD row-band remap (gy % 8 == 0 for all our launches)
  const int Lw = blockIdx.y * gridDim.x + blockIdx.x;
  const int bandRows = gridDim.y >> 3;
  const int j = Lw >> 3;
  const int colIdx = j / bandRows;
  const int rowLoc = j - colIdx * bandRows;
  const int bm = ((Lw & 7) * bandRows + rowLoc) * BM;
  const int bn = colIdx * BN;
  const int wave = tid >> 6;
  const int wr = (wave >> 1) * 64;
  const int wc = (wave & 1) * 64;
  f32x16 acc[2][2] = {};
  const int tr = tid >> 2;
  const int gt = tid & 3;
  const int gsw = (gt ^ ((tr >> 1) & 3)) * 8;   // inverse-swizzled source granule
  const int kbeg = (KSPLIT > 1) ? blockIdx.z * (K / KSPLIT) : 0;
  const bf16* Ag = A + (size_t)(bm + tr) * K + kbeg + gsw;
  const bf16* Bg = B + (size_t)(bn + tr) * K + kbeg + gsw;
  const int lofs = tr * BK + gt * 8;
  const int r31 = lane & 31, rh = lane >> 5;
  const int asw = (r31 >> 1) & 3;               // read-side swizzle (row bits 2:1)
  const int nst = K / KSPLIT / BK;
#define STAGE(buf, t)                                                         \
  do { const int bk_ = (t) * BK;                                              \
    GLDS16(Ag + bk_, sA[buf] + lofs);                                         \
    GLDS16(Ag + (size_t)64 * K + bk_, sA[buf] + lofs + 64 * BK);              \
    GLDS16(Bg + bk_, sB[buf] + lofs);                                         \
    GLDS16(Bg + (size_t)64 * K + bk_, sB[buf] + lofs + 64 * BK);              \
  } while (0)
  STAGE(0, 0);
  STAGE(1, 1);
  int cur = 0;
  for (int t = 0; t < nst; ++t) {
    if (t + 2 < nst) {
      const int nb = cur + 2 >= 3 ? cur - 1 : cur + 2;
      STAGE(nb, t + 2);
      asm volatile("s_waitcnt vmcnt(8)" ::: "memory");
    } else if (t + 1 < nst) {
      asm volatile("s_waitcnt vmcnt(4)" ::: "memory");
    } else {
      asm volatile("s_waitcnt vmcnt(0)" ::: "memory");
    }
    BARRIER();
    bf16x8 af[2][2], bfr[2][2];
    #pragma unroll
    for (int ks = 0; ks < 2; ++ks) {
      const int pos = ((ks * 2 + rh) ^ asw) * 8;
      #pragma unroll
      for (int i = 0; i < 2; ++i) {
        af[i][ks]  = *(const bf16x8*)(sA[cur] + (wr + i * 32 + r31) * BK + pos);
        bfr[i][ks] = *(const bf16x8*)(sB[cur] + (wc + i * 32 + r31) * BK + pos);
      }
    }
    #pragma unroll
    for (int ks = 0; ks < 2; ++ks)
      #pragma unroll
      for (int i = 0; i < 2; ++i)
        #pragma unroll
        for (int j2 = 0; j2 < 2; ++j2)
          acc[i][j2] = __builtin_amdgcn_mfma_f32_32x32x16_bf16(af[i][ks], bfr[j2][ks], acc[i][j2], 0, 0, 0);
    BARRIER();
    cur = cur == 2 ? 0 : cur + 1;
  }
#undef STAGE
  // C/D 32x32 layout: col = lane&31, row = (reg&3) + 8*(reg>>2) + 4*(lane>>5)
  const bool second = (KSPLIT > 1) && (blockIdx.z != 0);
  bf16* Co = second ? C1 : C0;
  #pragma unroll
  for (int j2 = 0; j2 < 2; ++j2) {
    const int col = bn + wc + j2 * 32 + r31;
    const float bv = second ? 0.f : bias[col];
    #pragma unroll
    for (int i = 0; i < 2; ++i) {
      const int row0 = bm + wr + i * 32 + 4 * rh;
      #pragma unroll
      for (int reg = 0; reg < 16; ++reg) {
        const int row = row0 + (reg & 3) + 8 * (reg >> 2);
        float v = acc[i][j2][reg] + bv;
        if (GELU) {
          // tanh-approx GELU via hw exp (clamped against overflow)
          float u = 0.7978845608f * (v + 0.044715f * v * v * v);
          u = fmaxf(fminf(u, 15.f), -15.f);
          const float e = __expf(-2.f * u);
          v = v / (1.f + e);             // 0.5*v*(1+tanh(u)) == v/(1+e^{-2u})
        }
        Co[(size_t)row * N + col] = (bf16)v;
      }
    }
  }
}

// ------------------------------------------------------------------- vt ----
// VT[bh][hd][tok] = qkv[bb*1024+tok][1536 + h*64 + hd]; swizzled LDS stage.
__global__ __launch_bounds__(256) void vt_kernel(const bf16* __restrict__ qkv,
                                                 bf16* __restrict__ VT) {
  const int tt = blockIdx.x;   // 16 tok tiles of 64
  const int bh = blockIdx.y;   // 96
  const int bb = bh / HEADS;
  const int h = bh - bb * HEADS;
  __shared__ bf16 sT[64 * 64];
  const int t = threadIdx.x;
  const int srow = t >> 3;            // 0..31 (tok within half-tile)
  const int g = t & 7;                // 16B granule
  const int gs = ((g ^ (srow & 7)) * 8);
  const bf16* Vg = qkv + ((size_t)(bb * SEQ + tt * 64 + srow)) * 2304 + 1536 + h * 64;
  GLDS16(Vg + gs, sT + srow * 64 + g * 8);
  GLDS16(Vg + (size_t)32 * 2304 + gs, sT + (32 + srow) * 64 + g * 8);
  __syncthreads();
  const int hd = t >> 2;
  const int tg = (t & 3) * 16;
  bf16 tmp[16];
  #pragma unroll
  for (int j = 0; j < 16; ++j) {
    const int tok = tg + j;
    tmp[j] = sT[tok * 64 + (hd ^ ((tok & 7) << 3))];
  }
  bf16* op = VT + (size_t)bh * (HD * SEQ) + (size_t)hd * SEQ + tt * 64 + tg;
  *(bf16x8*)(op) = *(const bf16x8*)(tmp);
  *(bf16x8*)(op + 8) = *(const bf16x8*)(tmp + 8);
}

// ----------------------------------------------------------------- attn ----
// VERBATIM R13 (passed timed replays). QBLK=128 (8 waves / 512 threads),
// fixed-max softmax, ones-row MFMA row-sum, 2-buffer K/V ring, swizzled LDS,
// XCD-chunked mapping, setprio.
__global__ __launch_bounds__(512) void attn_kernel(
    const bf16* __restrict__ qkv, const bf16* __restrict__ VT,
    bf16* __restrict__ out) {
  const int lin = blockIdx.x;            // 768 blocks
  const int qt = (lin >> 3) & 7;         // 8 q-tiles of 128
  const int bh = (lin & 7) + 8 * (lin >> 6);
  const int bb = bh / HEADS;
  const int h = bh - bb * HEADS;
  const int tid = threadIdx.x;
  const int lane = tid & 63;
  const int wave = tid >> 6;             // 0..7
  const size_t tokBase = (size_t)bb * SEQ;
  const int q0 = qt * 128;

  __shared__ bf16 sQ[128 * 64];     // 16 KB
  __shared__ bf16 sK[2][64 * 64];   // 16 KB
  __shared__ bf16 sV[2][80 * 64];   // 20 KB; rows 64.. = ones row + zeros
  __shared__ bf16 sP[8][16 * 64];   // 16 KB, per wave, swizzled

  for (int idx = tid; idx < 16 * 64; idx += 512) {
    const bf16 v = (idx < 64) ? (bf16)1.f : (bf16)0.f;
    sV[0][64 * 64 + idx] = v;
    sV[1][64 * 64 + idx] = v;
  }

  {
    #pragma unroll
    for (int kq = 0; kq < 2; ++kq) {
      const int slot = tid + kq * 512;
      const int qr = slot >> 3;
      const int qg = slot & 7;
      const bf16* Qg = qkv + (tokBase + q0 + qr) * 2304 + h * 64;
      GLDS16(Qg + ((qg ^ (qr & 7)) * 8), sQ + qr * 64 + qg * 8);
    }
  }
  const int srow = tid >> 3;          // 0..63
  const int g = tid & 7;
  const int gs = ((g ^ (srow & 7)) * 8);
  const bf16* Kbase = qkv + tokBase * 2304 + 768 + h * 64;
  const bf16* Vbase = VT + (size_t)bh * (HD * SEQ);
  GLDS16(Kbase + (size_t)srow * 2304 + gs, sK[0] + srow * 64 + g * 8);
  GLDS16(Vbase + (size_t)srow * SEQ + gs, sV[0] + srow * 64 + g * 8);
  __syncthreads();

  const int l15 = lane & 15, hi = lane >> 4;
  const int ksw = (l15 & 7) << 3;
  bf16x8 qf[2];
  {
    const int qrow = wave * 16 + l15;
    const int qsw = (qrow & 7) << 3;
    #pragma unroll
    for (int ks = 0; ks < 2; ++ks)
      qf[ks] = *(const bf16x8*)(sQ + qrow * 64 + ((hi * 8 + ks * 32) ^ qsw));
  }

  f32x4 o[5] = {};

  for (int it = 0; it < SEQ / 64; ++it) {
    const int cur = it & 1;
    if (it + 1 < SEQ / 64) {
      const int kb = (it + 1) * 64;
      GLDS16(Kbase + (size_t)(kb + srow) * 2304 + gs, sK[cur ^ 1] + srow * 64 + g * 8);
      GLDS16(Vbase + (size_t)srow * SEQ + kb + gs, sV[cur ^ 1] + srow * 64 + g * 8);
      asm volatile("s_waitcnt vmcnt(2)" ::: "memory");
    } else {
      asm volatile("s_waitcnt vmcnt(0)" ::: "memory");
    }
    BARRIER();
    f32x4 s[4];
    __builtin_amdgcn_s_setprio(1);
    #pragma unroll
    for (int nj = 0; nj < 4; ++nj) {
      s[nj] = (f32x4){0.f, 0.f, 0.f, 0.f};
      #pragma unroll
      for (int ks = 0; ks < 2; ++ks) {
        bf16x8 kf = *(const bf16x8*)(sK[cur] + (nj * 16 + l15) * 64 + ((hi * 8 + ks * 32) ^ ksw));
        s[nj] = __builtin_amdgcn_mfma_f32_16x16x32_bf16(qf[ks], kf, s[nj], 0, 0, 0);
      }
    }
    __builtin_amdgcn_s_setprio(0);
    bf16* Pw = sP[wave];
    #pragma unroll
    for (int r = 0; r < 4; ++r) {
      const int prow = hi * 4 + r;
      const int psw = (prow & 7) << 3;
      #pragma unroll
      for (int nj = 0; nj < 4; ++nj)
        Pw[prow * 64 + ((nj * 16 + l15) ^ psw)] = (bf16)__expf(s[nj][r] * 0.125f);
    }
    __builtin_amdgcn_s_setprio(1);
    #pragma unroll
    for (int ks = 0; ks < 2; ++ks) {
      bf16x8 pa = *(const bf16x8*)(Pw + l15 * 64 + ((hi * 8 + ks * 32) ^ ksw));
      #pragma unroll
      for (int nj = 0; nj < 5; ++nj) {
        bf16x8 vb = *(const bf16x8*)(sV[cur] + (nj * 16 + l15) * 64 + ((hi * 8 + ks * 32) ^ ksw));
        o[nj] = __builtin_amdgcn_mfma_f32_16x16x32_bf16(pa, vb, o[nj], 0, 0, 0);
      }
    }
    __builtin_amdgcn_s_setprio(0);
    BARRIER();
  }
  #pragma unroll
  for (int r = 0; r < 4; ++r) {
    const float lsum = __shfl(o[4][r], hi << 4, 64);   // lane (hi,l15=0) holds l
    const float inv = 1.f / lsum;
    const size_t row = tokBase + q0 + wave * 16 + hi * 4 + r;
    bf16* orow = out + row * EMBED + h * 64;
    #pragma unroll
    for (int nj = 0; nj < 4; ++nj)
      orow[nj * 16 + l15] = (bf16)(o[nj][r] * inv);
  }
}

// -------------------------------------------------------- combine+preln ----
// Fused block-1 exit / block-2 entry. TWO=1: transform = t + t2 (split-K).
template <int TWO>
__global__ __launch_bounds__(256) void combine_preln_kernel(
    const float* __restrict__ x, const bf16* __restrict__ t,
    const bf16* __restrict__ t2,
    const float* __restrict__ Hres, const float* __restrict__ Hpost,
    const float* __restrict__ Hpre2,
    const float* __restrict__ g2, const float* __restrict__ b2,
    float* __restrict__ X2, bf16* __restrict__ LN) {
  const int tok = blockIdx.x;
  const int tid = threadIdx.x;
  __shared__ float s[CHUNK];
  __shared__ float part[8];
  __shared__ float red[2];
  float sv = 0.f;
  if (tid < CHUNK) {
    const float* xr = x + (size_t)tok * EMBED + tid;
    const bf16* tr = t + (size_t)tok * EMBED + tid;
    const float x0 = xr[0], x1 = xr[CHUNK], x2v = xr[2 * CHUNK], x3 = xr[3 * CHUNK];
    float tm = (float)tr[0] + (float)tr[CHUNK] + (float)tr[2 * CHUNK] + (float)tr[3 * CHUNK];
    if (TWO) {
      const bf16* t2r = t2 + (size_t)tok * EMBED + tid;
      tm += (float)t2r[0] + (float)t2r[CHUNK] + (float)t2r[2 * CHUNK] + (float)t2r[3 * CHUNK];
    }
    tm *= 0.25f;
    float* orow = X2 + (size_t)tok * EMBED + tid;
    #pragma unroll
    for (int n = 0; n < 4; ++n) {
      const float v = Hres[4*n+0]*x0 + Hres[4*n+1]*x1 + Hres[4*n+2]*x2v + Hres[4*n+3]*x3
                    + Hpost[n] * tm;
      orow[n * CHUNK] = v;
      sv += Hpre2[n] * v;
    }
    s[tid] = sv;
  }
  float sum = sv, sq = sv * sv;
  #pragma unroll
  for (int m = 32; m > 0; m >>= 1) {
    sum += __shfl_down(sum, m);
    sq  += __shfl_down(sq, m);
  }
  if ((tid & 63) == 0) { part[tid >> 6] = sum; part[4 + (tid >> 6)] = sq; }
  __syncthreads();
  if (tid == 0) {
    float S = part[0] + part[1] + part[2] + part[3];
    float Q = part[4] + part[5] + part[6] + part[7];
    float mu = S * (1.f / CHUNK);
    float var = Q * (1.f / CHUNK) - mu * mu;
    red[0] = mu;
    red[1] = rsqrtf(var + 1e-5f);
  }
  __syncthreads();
  const float mu = red[0], rs = red[1];
  bf16* lrow = LN + (size_t)tok * EMBED;
  #pragma unroll
  for (int r = 0; r < 3; ++r) {
    const int d = tid + r * 256;
    lrow[d] = (bf16)((s[d % CHUNK] - mu) * rs * g2[d] + b2[d]);
  }
}

// -------------------------------------------------------------- combine ----
// Final combine (writes f32 d_out). TWO=1: transform = t + t2 (split-K).
template <int TWO>
__global__ void combine_kernel(const float* __restrict__ xs, const bf16* __restrict__ t,
                               const bf16* __restrict__ t2,
                               const float* __restrict__ Hres, const float* __restrict__ Hpost,
                               float* __restrict__ outp) {
  const int idx = blockIdx.x * 256 + threadIdx.x;
  if (idx >= TOKENS * CHUNK) return;
  const int tok = idx / CHUNK;
  const int c = idx - tok * CHUNK;
  const float* xr = xs + (size_t)tok * EMBED + c;
  const bf16* tr = t + (size_t)tok * EMBED + c;
  const float x0 = xr[0], x1 = xr[CHUNK], x2 = xr[2 * CHUNK], x3 = xr[3 * CHUNK];
  float tm = (float)tr[0] + (float)tr[CHUNK] + (float)tr[2 * CHUNK] + (float)tr[3 * CHUNK];
  if (TWO) {
    const bf16* t2r = t2 + (size_t)tok * EMBED + c;
    tm += (float)t2r[0] + (float)t2r[CHUNK] + (float)t2r[2 * CHUNK] + (float)t2r[3 * CHUNK];
  }
  tm *= 0.25f;
  #pragma unroll
  for (int n = 0; n < 4; ++n) {
    const float v = Hres[4*n+0]*x0 + Hres[4*n+1]*x1 + Hres[4*n+2]*x2 + Hres[4*n+3]*x3
                  + Hpost[n] * tm;
    outp[(size_t)tok * EMBED + n * CHUNK + c] = v;
  }
}

// ---------------------------------------------------------------- launch ---
extern "C" void kernel_launch(void* const* d_in, const int* in_sizes, int n_in,
                              void* d_out, int out_size, void* d_ws, size_t ws_size,
                              hipStream_t stream) {
  const float* x       = (const float*)d_in[0];
  const float* ln1_g   = (const float*)d_in[1];
  const float* ln1_b   = (const float*)d_in[2];
  const float* ln2_g   = (const float*)d_in[3];
  const float* ln2_b   = (const float*)d_in[4];
  const float* qkv_w   = (const float*)d_in[5];
  const float* qkv_b   = (const float*)d_in[6];
  const float* proj_w  = (const float*)d_in[7];
  const float* proj_b  = (const float*)d_in[8];
  const float* fc1_w   = (const float*)d_in[9];
  const float* fc1_b   = (const float*)d_in[10];
  const float* fc2_w   = (const float*)d_in[11];
  const float* fc2_b   = (const float*)d_in[12];
  const float* a_hres  = (const float*)d_in[13];
  const float* a_hpre  = (const float*)d_in[14];
  const float* a_hpost = (const float*)d_in[15];
  const float* m_hres  = (const float*)d_in[16];
  const float* m_hpre  = (const float*)d_in[17];
  const float* m_hpost = (const float*)d_in[18];

  char* ws = (char*)d_ws;
  float* HS = (float*)(ws);                                  // 48 floats
  bf16* Wq  = (bf16*)(ws + 1024);                            // 2304x768
  bf16* Wp  = (bf16*)(ws + 1024 + 3538944);                  // 768x768
  bf16* W1  = (bf16*)(ws + 1024 + 3538944 + 1179648);        // 3072x768
  bf16* W2  = (bf16*)(ws + 1024 + 3538944 + 1179648 + 4718592); // 768x3072
  bf16* LN  = (bf16*)(ws + 14156800);                        // 8192x768 bf16
  bf16* T   = (bf16*)(ws + 26739712);                        // 8192x768 bf16
  bf16* PT  = (bf16*)(ws + 39322624);                        // 8192x768 bf16 (split-K partial)
  float* X2 = (float*)(ws + 51905536);                       // 8192x768 f32
  bf16* QKV = (bf16*)(ws + 77071360);                        // 8192x2304 bf16
  bf16* AO  = (bf16*)(ws + 114820096);                       // 8192x768 bf16
  bf16* Hm  = (bf16*)(ws + 77071360);                        // 8192x3072 (overlays QKV+AO)
  bf16* VT  = LN;   // 96x64x1024 bf16 — overlays LN (dead after qkv GEMM)

  // fused: preln block-1 (blocks 0..8191) + weight cvt (8192..10239)
  //        + Sinkhorn/softmax prep (block 10240)
  head_kernel<<<TOKENS + 2049, 256, 0, stream>>>(
      x, ln1_g, ln1_b, LN,
      qkv_w, proj_w, fc1_w, fc2_w, Wq, Wp, W1, W2,
      a_hres, a_hpre, a_hpost, m_hres, m_hpre, m_hpost, HS);

  // ---- block 1: attention mhc ----
  gemm_bt<0, 1><<<dim3(2304 / 128, TOKENS / 128), 256, 0, stream>>>(
      LN, Wq, qkv_b, QKV, nullptr, TOKENS, 2304, 768);
  vt_kernel<<<dim3(16, 96), 256, 0, stream>>>(QKV, VT);
  attn_kernel<<<768, 512, 0, stream>>>(QKV, VT, AO);
  // proj with split-K=2 (K=768 -> 2x384): 768 blocks
  gemm_bt<0, 2><<<dim3(768 / 128, TOKENS / 128, 2), 256, 0, stream>>>(
      AO, Wp, proj_b, T, PT, TOKENS, 768, 768);
  // fused: combine block-1 (T+PT) + preLN block-2 (writes X2 f32 + LN bf16)
  combine_preln_kernel<1><<<TOKENS, 256, 0, stream>>>(
      x, T, PT, HS + 0, HS + 20, HS + 24 + 16, ln2_g, ln2_b, X2, LN);

  // ---- block 2: MLP mhc ----
  gemm_bt<1, 1><<<dim3(3072 / 128, TOKENS / 128), 256, 0, stream>>>(
      LN, W1, fc1_b, Hm, nullptr, TOKENS, 3072, 768);
  gemm_bt<0, 2><<<dim3(768 / 128, TOKENS / 128, 2), 256, 0, stream>>>(
      Hm, W2, fc2_b, T, PT, TOKENS, 768, 3072);
  combine_kernel<1><<<(TOKENS * CHUNK + 255) / 256, 256, 0, stream>>>(
      X2, T, PT, HS + 24, HS + 24 + 20, (float*)d_out);
}